// Round 18
// baseline (1173.023 us; speedup 1.0000x reference)
//
#include <hip/hip_runtime.h>
#include <math.h>

#define B_ 256
#define N_ 127
#define S_ 128
#define NDIM_ 3
#define D_ 256
#define H_ 8
#define DH_ 32
#define M_ 256
#define HID_ 256
#define L_ 4
#define LOG2E 1.44269504088896340736f

typedef __attribute__((ext_vector_type(8))) short short8;
typedef __attribute__((ext_vector_type(4))) short bfx4;
typedef __attribute__((ext_vector_type(4))) float floatx4;

// ---------- bf16 split helpers ----------
__device__ __forceinline__ ushort bf16_rn(float x) {
    unsigned u = __float_as_uint(x);
    u = (u + 0x7fffu + ((u >> 16) & 1u)) >> 16;
    return (ushort)u;
}
__device__ __forceinline__ unsigned split_pack(float x) {
    const ushort h = bf16_rn(x);
    const float r = x - __uint_as_float(((unsigned)h) << 16);
    const ushort l = bf16_rn(r);
    return (unsigned)h | ((unsigned)l << 16);
}
__device__ __forceinline__ float rec(unsigned u) {
    return __uint_as_float(u << 16) + __uint_as_float(u & 0xffff0000u);
}
__device__ __forceinline__ unsigned hpair(unsigned u0, unsigned u1) {
    return (u0 & 0xffffu) | (u1 << 16);
}
__device__ __forceinline__ unsigned lpair(unsigned u0, unsigned u1) {
    return (u0 >> 16) | (u1 & 0xffff0000u);
}

// ---------- block reductions ----------
__device__ __forceinline__ float blk_sum(float v, float* sred) {
#pragma unroll
    for (int o = 32; o > 0; o >>= 1) v += __shfl_xor(v, o, 64);
    if ((threadIdx.x & 63) == 0) sred[threadIdx.x >> 6] = v;
    __syncthreads();
    v = sred[0] + sred[1] + sred[2] + sred[3];
    __syncthreads();
    return v;
}

// ---------- fused prep: weight planes + proj conv + slot reset + embedding ----------
__global__ void __launch_bounds__(256) k_prep(
    const float* __restrict__ Wq, const float* __restrict__ Wk, const float* __restrict__ Wv,
    const float* __restrict__ Wo, const float* __restrict__ f1w, const float* __restrict__ f2w,
    const float* __restrict__ proj, ushort* __restrict__ WH, ushort* __restrict__ WL,
    unsigned* __restrict__ P2, int* __restrict__ slots,
    const float* __restrict__ x, const float* __restrict__ ew, const float* __restrict__ eb,
    unsigned* __restrict__ Aout)
{
    const int bid = blockIdx.x;
    if (bid < 768) {
        const int tensor = bid / 128;
        const int tid = (bid & 127) * 256 + threadIdx.x;
        const float* src = tensor == 0 ? Wq : tensor == 1 ? Wk : tensor == 2 ? Wv
                         : tensor == 3 ? Wo : tensor == 4 ? f1w : f2w;
        ushort* dh = WH + (size_t)tensor * L_ * 65536;
        ushort* dl = WL + (size_t)tensor * L_ * 65536;
        const int l = tid >> 13;
        const int col = (tid >> 5) & 255, kc = tid & 31;
        const float* sp = src + ((size_t)l << 16) + col * 256 + kc * 8;
        float v[8];
        *(float4*)&v[0] = *(const float4*)sp;
        *(float4*)&v[4] = *(const float4*)(sp + 4);
        unsigned hu[4], lu[4];
#pragma unroll
        for (int i = 0; i < 4; i++) {
            const unsigned u0 = split_pack(v[2 * i]);
            const unsigned u1 = split_pack(v[2 * i + 1]);
            hu[i] = hpair(u0, u1);
            lu[i] = lpair(u0, u1);
        }
        const size_t off = ((size_t)l << 16) + ((size_t)(kc * 256 + col)) * 8;
        *(uint4*)&dh[off] = make_uint4(hu[0], hu[1], hu[2], hu[3]);
        *(uint4*)&dl[off] = make_uint4(lu[0], lu[1], lu[2], lu[3]);
    } else if (bid < 800) {
        const int idx = ((bid - 768) * 256 + threadIdx.x) * 4;
        const float4 w4 = *(const float4*)&proj[idx];
        const float v[4] = {w4.x, w4.y, w4.z, w4.w};
        unsigned u[4];
#pragma unroll
        for (int i = 0; i < 4; i++) u[i] = split_pack(v[i]);
        *(uint4*)&P2[idx] = make_uint4(u[0], u[1], u[2], u[3]);
    } else if (bid == 800) {
        if (threadIdx.x < 4) {
            const int i = __float_as_int(-INFINITY);
            slots[threadIdx.x] = (i >= 0) ? i : (i ^ 0x7fffffff);
        }
    } else {
        const int idx4 = (bid - 801) * 256 + threadIdx.x;
        const int d0 = (idx4 & 63) * 4;
        const int n = (idx4 >> 6) & (S_ - 1);
        const int b = idx4 >> 13;
        unsigned r[4] = {0u, 0u, 0u, 0u};
        if (n > 0) {
            const float* xr = x + ((size_t)b * N_ + (n - 1)) * NDIM_;
            const float x0 = xr[0], x1 = xr[1], x2 = xr[2];
#pragma unroll
            for (int j = 0; j < 4; j++) {
                const int d = d0 + j;
                const float val = eb[d] + x0 * ew[d * 3 + 0] + x1 * ew[d * 3 + 1] + x2 * ew[d * 3 + 2];
                r[j] = split_pack(val);
            }
        }
        *(uint4*)&Aout[(size_t)idx4 * 4] = make_uint4(r[0], r[1], r[2], r[3]);
    }
}

// ---------- single-pass QKV GEMM: A resident in LDS, 3 weight streams ----------
// 64-row blocks (grid 512, 512 threads). A tile (64x256 packed) staged ONCE as
// h/l planes (66.6 KB -> 2 blocks/CU); then which=0,1,2 run barrier-free K-loops
// (A from resident LDS, W direct from global planes). Per-output MFMA order is
// identical to the 3-dispatch version -> bit-identical Q/K/V.
__global__ void __launch_bounds__(512, 2) k_gemm_qkv(
    const unsigned* __restrict__ Ap, const ushort* __restrict__ WHb,
    const ushort* __restrict__ WLb, const int l,
    const float* __restrict__ bq, const float* __restrict__ bk, const float* __restrict__ bv_,
    const int* __restrict__ mask,
    unsigned* __restrict__ Qo, unsigned* __restrict__ Ko, unsigned* __restrict__ Vo)
{
    __shared__ ushort sAh[32 * 520];           // [kc(32)][64 rows][8] (+8 pad/kc)
    __shared__ ushort sAl[32 * 520];
    const int t = threadIdx.x;
    const int w = t >> 6, lane = t & 63;
    const int quad = lane >> 4, l16 = lane & 15;
    const int rowbase = 32 * (w >> 2), colbase = 64 * (w & 3);
    const int row0 = blockIdx.x * 64;

    // stage full A tile once: thread (row=t>>3, kcg=(t&7)*4 .. +3)
    {
        const int row = t >> 3, kcg = (t & 7) * 4;
        const unsigned* arow = Ap + (size_t)(row0 + row) * D_;
#pragma unroll
        for (int j = 0; j < 4; j++) {
            const int kc = kcg + j;
            const unsigned* src = arow + kc * 8;
            const uint4 a0 = *(const uint4*)src;
            const uint4 a1 = *(const uint4*)(src + 4);
            const int ai = kc * 520 + row * 8;
            *(uint4*)&sAh[ai] = make_uint4(hpair(a0.x, a0.y), hpair(a0.z, a0.w),
                                           hpair(a1.x, a1.y), hpair(a1.z, a1.w));
            *(uint4*)&sAl[ai] = make_uint4(lpair(a0.x, a0.y), lpair(a0.z, a0.w),
                                           lpair(a1.x, a1.y), lpair(a1.z, a1.w));
        }
    }
    __syncthreads();

    const int b = row0 >> 7;
#pragma unroll
    for (int which = 0; which < 3; which++) {
        const ushort* WH = WHb + ((size_t)(which * L_ + l)) * 65536;
        const ushort* WL = WLb + ((size_t)(which * L_ + l)) * 65536;
        const float* bias = which == 0 ? bq : which == 1 ? bk : bv_;
        unsigned* out = which == 0 ? Qo : which == 1 ? Ko : Vo;

        floatx4 acc[2][4];
#pragma unroll
        for (int rt = 0; rt < 2; rt++)
#pragma unroll
            for (int ct = 0; ct < 4; ct++) acc[rt][ct] = (floatx4){0.f, 0.f, 0.f, 0.f};

        for (int s = 0; s < 8; s++) {
            const size_t wbase = ((size_t)((s * 4 + quad) * 256 + colbase + l16)) * 8;
            const ushort* WHf = WH + wbase;
            const ushort* WLf = WL + wbase;
            short8 ah[2], al[2], wh[4], wl[4];
#pragma unroll
            for (int ct = 0; ct < 4; ct++) {
                wh[ct] = *(const short8*)&WHf[ct * 128];
                wl[ct] = *(const short8*)&WLf[ct * 128];
            }
#pragma unroll
            for (int rt = 0; rt < 2; rt++) {
                const int ai = (s * 4 + quad) * 520 + (rowbase + 16 * rt + l16) * 8;
                ah[rt] = *(const short8*)&sAh[ai];
                al[rt] = *(const short8*)&sAl[ai];
            }
#pragma unroll
            for (int rt = 0; rt < 2; rt++)
#pragma unroll
                for (int ct = 0; ct < 4; ct++) {
                    acc[rt][ct] = __builtin_amdgcn_mfma_f32_16x16x32_bf16(ah[rt], wh[ct], acc[rt][ct], 0, 0, 0);
                    acc[rt][ct] = __builtin_amdgcn_mfma_f32_16x16x32_bf16(ah[rt], wl[ct], acc[rt][ct], 0, 0, 0);
                    acc[rt][ct] = __builtin_amdgcn_mfma_f32_16x16x32_bf16(al[rt], wh[ct], acc[rt][ct], 0, 0, 0);
                }
        }

        int colv[4]; float bv[4];
#pragma unroll
        for (int ct = 0; ct < 4; ct++) { colv[ct] = colbase + 16 * ct + l16; bv[ct] = bias[colv[ct]]; }
#pragma unroll
        for (int rt = 0; rt < 2; rt++)
#pragma unroll
        for (int i = 0; i < 4; i++) {
            const int rl = rowbase + 16 * rt + quad * 4 + i;
            const int n = (row0 + rl) & (S_ - 1);
            float keep = 1.f;
            if (which == 2) keep = (n == 0) ? 1.f : (mask[b * N_ + n - 1] ? 0.f : 1.f);
#pragma unroll
            for (int ct = 0; ct < 4; ct++) {
                float c = acc[rt][ct][i] + bv[ct];
                if (which == 2) c *= keep;
                const int col = colv[ct];
                out[(((size_t)b * H_ + (col >> 5)) * S_ + n) * DH_ + (col & 31)] = split_pack(c);
            }
        }
    }
}

// ---------- fused Wo+LN1+FFN+LN2 mega-kernel (64-row blocks, grid 512) ----------
__global__ void __launch_bounds__(512, 2) k_wofn(
    const unsigned* __restrict__ Ap,
    const ushort* __restrict__ WoH, const ushort* __restrict__ WoL,
    const ushort* __restrict__ W1H, const ushort* __restrict__ W1L,
    const ushort* __restrict__ W2H, const ushort* __restrict__ W2L,
    const float* __restrict__ bo, const float* __restrict__ n1w, const float* __restrict__ n1b,
    const float* __restrict__ b1, const float* __restrict__ b2,
    const float* __restrict__ g2w, const float* __restrict__ g2b,
    unsigned* __restrict__ out)
{
    __shared__ char smemc[67584];
    ushort* Th  = (ushort*)smemc;              // [64][264] T planes; later G1
    ushort* Tl  = (ushort*)(smemc + 33792);
    ushort* sTh = (ushort*)smemc;              // [2][2080] A staging (alias, dead first)
    ushort* sTl = (ushort*)(smemc + 8320);
    __shared__ float sredA[64][8], sredB[64][8];
    const int t = threadIdx.x;
    const int w = t >> 6, lane = t & 63;
    const int quad = lane >> 4, l16 = lane & 15;
    const int row0 = blockIdx.x * 64;

    // ---- stage 0: T^T = Wo^T x A^T ----
    floatx4 acc[2][4];
#pragma unroll
    for (int rt = 0; rt < 2; rt++)
#pragma unroll
        for (int ct = 0; ct < 4; ct++) acc[rt][ct] = (floatx4){0.f, 0.f, 0.f, 0.f};

    const int arow = t >> 3, akq = t & 7;
    const unsigned* AG = Ap + (size_t)(row0 + arow) * D_ + akq * 4;
    const int aidx = (akq >> 1) * 520 + arow * 8 + (akq & 1) * 4;

    {
        const uint4 a4 = *(const uint4*)AG;
        *(uint2*)&sTh[aidx] = make_uint2(hpair(a4.x, a4.y), hpair(a4.z, a4.w));
        *(uint2*)&sTl[aidx] = make_uint2(lpair(a4.x, a4.y), lpair(a4.z, a4.w));
    }
    __syncthreads();

    for (int s = 0; s < 8; s++) {
        const int p = s & 1;
        uint4 a_n;
        if (s + 1 < 8) a_n = *(const uint4*)(AG + (s + 1) * 32);
        const size_t wbase = ((size_t)((s * 4 + quad) * 256 + 32 * w + l16)) * 8;
        short8 fh[2], fl[2], th[4], tl[4];
#pragma unroll
        for (int rt = 0; rt < 2; rt++) {
            fh[rt] = *(const short8*)&WoH[wbase + rt * 128];
            fl[rt] = *(const short8*)&WoL[wbase + rt * 128];
        }
#pragma unroll
        for (int ct = 0; ct < 4; ct++) {
            const int ti = p * 2080 + quad * 520 + (16 * ct + l16) * 8;
            th[ct] = *(const short8*)&sTh[ti];
            tl[ct] = *(const short8*)&sTl[ti];
        }
#pragma unroll
        for (int rt = 0; rt < 2; rt++)
#pragma unroll
            for (int ct = 0; ct < 4; ct++) {
                acc[rt][ct] = __builtin_amdgcn_mfma_f32_16x16x32_bf16(fh[rt], th[ct], acc[rt][ct], 0, 0, 0);
                acc[rt][ct] = __builtin_amdgcn_mfma_f32_16x16x32_bf16(fl[rt], th[ct], acc[rt][ct], 0, 0, 0);
                acc[rt][ct] = __builtin_amdgcn_mfma_f32_16x16x32_bf16(fh[rt], tl[ct], acc[rt][ct], 0, 0, 0);
            }
        if (s + 1 < 8) {
            *(uint2*)&sTh[(p ^ 1) * 2080 + aidx] = make_uint2(hpair(a_n.x, a_n.y), hpair(a_n.z, a_n.w));
            *(uint2*)&sTl[(p ^ 1) * 2080 + aidx] = make_uint2(lpair(a_n.x, a_n.y), lpair(a_n.z, a_n.w));
        }
        __syncthreads();
    }

    // ---- LN1 epilogue on T^T layout ----
    {
        float bov[2][4];
#pragma unroll
        for (int rt = 0; rt < 2; rt++)
#pragma unroll
            for (int i = 0; i < 4; i++) bov[rt][i] = bo[32 * w + 16 * rt + quad * 4 + i];
        float ps[4], ps2[4];
#pragma unroll
        for (int ct = 0; ct < 4; ct++) { ps[ct] = 0.f; ps2[ct] = 0.f; }
#pragma unroll
        for (int rt = 0; rt < 2; rt++)
#pragma unroll
        for (int ct = 0; ct < 4; ct++)
#pragma unroll
        for (int i = 0; i < 4; i++) {
            const float c = acc[rt][ct][i] + bov[rt][i];
            acc[rt][ct][i] = c;
            ps[ct] += c; ps2[ct] += c * c;
        }
#pragma unroll
        for (int ct = 0; ct < 4; ct++) {
            ps[ct] += __shfl_xor(ps[ct], 16, 64);  ps[ct] += __shfl_xor(ps[ct], 32, 64);
            ps2[ct] += __shfl_xor(ps2[ct], 16, 64); ps2[ct] += __shfl_xor(ps2[ct], 32, 64);
        }
        if (quad == 0) {
#pragma unroll
            for (int ct = 0; ct < 4; ct++) {
                sredA[16 * ct + l16][w] = ps[ct];
                sredB[16 * ct + l16][w] = ps2[ct];
            }
        }
        __syncthreads();
        float mu[4], rs[4];
#pragma unroll
        for (int ct = 0; ct < 4; ct++) {
            const int n = 16 * ct + l16;
            float s = 0.f, s2 = 0.f;
#pragma unroll
            for (int k = 0; k < 8; k++) { s += sredA[n][k]; s2 += sredB[n][k]; }
            mu[ct] = s * (1.f / D_);
            rs[ct] = rsqrtf(s2 * (1.f / D_) - mu[ct] * mu[ct] + 1e-5f);
        }
        float gv1[2][4], bv1[2][4];
#pragma unroll
        for (int rt = 0; rt < 2; rt++)
#pragma unroll
            for (int i = 0; i < 4; i++) {
                const int c2 = 32 * w + 16 * rt + quad * 4 + i;
                gv1[rt][i] = n1w[c2];
                bv1[rt][i] = n1b[c2];
            }
#pragma unroll
        for (int ct = 0; ct < 4; ct++) {
            const int n = 16 * ct + l16;
#pragma unroll
            for (int rt = 0; rt < 2; rt++) {
                unsigned u[4];
#pragma unroll
                for (int i = 0; i < 4; i++) {
                    const float tv = (acc[rt][ct][i] - mu[ct]) * rs[ct] * gv1[rt][i] + bv1[rt][i];
                    u[i] = split_pack(tv);
                }
                const int base = n * 264 + 32 * w + 16 * rt + quad * 4;
                *(uint2*)&Th[base] = make_uint2(hpair(u[0], u[1]), hpair(u[2], u[3]));
                *(uint2*)&Tl[base] = make_uint2(lpair(u[0], u[1]), lpair(u[2], u[3]));
            }
        }
        __syncthreads();
    }

    // ---- stage 1: G1^T = f1w^T x T (barrier-free K-loop over resident T) ----
    floatx4 acc1[2][4];
#pragma unroll
    for (int rt = 0; rt < 2; rt++)
#pragma unroll
        for (int ct = 0; ct < 4; ct++) acc1[rt][ct] = (floatx4){0.f, 0.f, 0.f, 0.f};

    for (int s = 0; s < 8; s++) {
        const size_t wbase = ((size_t)((s * 4 + quad) * 256 + 32 * w + l16)) * 8;
        short8 fh[2], fl[2], th[4], tl[4];
#pragma unroll
        for (int rt = 0; rt < 2; rt++) {
            fh[rt] = *(const short8*)&W1H[wbase + rt * 128];
            fl[rt] = *(const short8*)&W1L[wbase + rt * 128];
        }
#pragma unroll
        for (int ct = 0; ct < 4; ct++) {
            const int ti = (16 * ct + l16) * 264 + s * 32 + quad * 8;
            th[ct] = *(const short8*)&Th[ti];
            tl[ct] = *(const short8*)&Tl[ti];
        }
#pragma unroll
        for (int rt = 0; rt < 2; rt++)
#pragma unroll
            for (int ct = 0; ct < 4; ct++) {
                acc1[rt][ct] = __builtin_amdgcn_mfma_f32_16x16x32_bf16(fh[rt], th[ct], acc1[rt][ct], 0, 0, 0);
                acc1[rt][ct] = __builtin_amdgcn_mfma_f32_16x16x32_bf16(fl[rt], th[ct], acc1[rt][ct], 0, 0, 0);
                acc1[rt][ct] = __builtin_amdgcn_mfma_f32_16x16x32_bf16(fh[rt], tl[ct], acc1[rt][ct], 0, 0, 0);
            }
    }
    __syncthreads();   // all T reads done before G1 overwrites the planes

    {
        float b1v[2][4];
#pragma unroll
        for (int rt = 0; rt < 2; rt++)
#pragma unroll
            for (int i = 0; i < 4; i++) b1v[rt][i] = b1[32 * w + 16 * rt + quad * 4 + i];
#pragma unroll
        for (int ct = 0; ct < 4; ct++) {
            const int n = 16 * ct + l16;
#pragma unroll
            for (int rt = 0; rt < 2; rt++) {
                unsigned u[4];
#pragma unroll
                for (int i = 0; i < 4; i++) {
                    float c = acc1[rt][ct][i] + b1v[rt][i];
                    c = (c >= 0.f) ? c : 0.2f * c;
                    u[i] = split_pack(c);
                }
                const int base = n * 264 + 32 * w + 16 * rt + quad * 4;
                *(uint2*)&Th[base] = make_uint2(hpair(u[0], u[1]), hpair(u[2], u[3]));
                *(uint2*)&Tl[base] = make_uint2(lpair(u[0], u[1]), lpair(u[2], u[3]));
            }
        }
        __syncthreads();
    }

    // ---- stage 2: out = G1 * f2w + LN2 ----
    const int rowbase = 32 * (w >> 2), colbase = 64 * (w & 3);
    const int colg = w & 3;
    floatx4 acc2[2][4];
#pragma unroll
    for (int rt = 0; rt < 2; rt++)
#pragma unroll
        for (int ct = 0; ct < 4; ct++) acc2[rt][ct] = (floatx4){0.f, 0.f, 0.f, 0.f};

    for (int ks = 0; ks < 8; ks++) {
        const size_t w2base = ((size_t)((ks * 4 + quad) * 256 + colbase + l16)) * 8;
        short8 ah[2], al[2], wh[4], wl[4];
#pragma unroll
        for (int ct = 0; ct < 4; ct++) {
            wh[ct] = *(const short8*)&W2H[w2base + ct * 128];
            wl[ct] = *(const short8*)&W2L[w2base + ct * 128];
        }
#pragma unroll
        for (int rt = 0; rt < 2; rt++) {
            const int gi = (rowbase + 16 * rt + l16) * 264 + ks * 32 + quad * 8;
            ah[rt] = *(const short8*)&Th[gi];
            al[rt] = *(const short8*)&Tl[gi];
        }
#pragma unroll
        for (int rt = 0; rt < 2; rt++)
#pragma unroll
            for (int ct = 0; ct < 4; ct++) {
                acc2[rt][ct] = __builtin_amdgcn_mfma_f32_16x16x32_bf16(ah[rt], wh[ct], acc2[rt][ct], 0, 0, 0);
                acc2[rt][ct] = __builtin_amdgcn_mfma_f32_16x16x32_bf16(ah[rt], wl[ct], acc2[rt][ct], 0, 0, 0);
                acc2[rt][ct] = __builtin_amdgcn_mfma_f32_16x16x32_bf16(al[rt], wh[ct], acc2[rt][ct], 0, 0, 0);
            }
    }
    __syncthreads();

    int colv[4]; float bv[4], gv[4], bbv[4];
#pragma unroll
    for (int ct = 0; ct < 4; ct++) {
        colv[ct] = colbase + 16 * ct + l16;
        bv[ct] = b2[colv[ct]];
        gv[ct] = g2w[colv[ct]];
        bbv[ct] = g2b[colv[ct]];
    }
#pragma unroll
    for (int rt = 0; rt < 2; rt++)
#pragma unroll
    for (int i = 0; i < 4; i++) {
        const int rl = rowbase + 16 * rt + quad * 4 + i;
        float s = 0.f, s2 = 0.f;
#pragma unroll
        for (int ct = 0; ct < 4; ct++) {
            const float c = acc2[rt][ct][i] + bv[ct];
            s += c; s2 += c * c;
        }
#pragma unroll
        for (int o = 8; o > 0; o >>= 1) { s += __shfl_xor(s, o, 64); s2 += __shfl_xor(s2, o, 64); }
        if (l16 == 0) { sredA[rl][colg] = s; sredB[rl][colg] = s2; }
    }
    __syncthreads();
#pragma unroll
    for (int rt = 0; rt < 2; rt++)
#pragma unroll
    for (int i = 0; i < 4; i++) {
        const int rl = rowbase + 16 * rt + quad * 4 + i;
        const float s = sredA[rl][0] + sredA[rl][1] + sredA[rl][2] + sredA[rl][3];
        const float s2 = sredB[rl][0] + sredB[rl][1] + sredB[rl][2] + sredB[rl][3];
        const float mu = s * (1.f / D_);
        const float rs = rsqrtf(s2 * (1.f / D_) - mu * mu + 1e-5f);
#pragma unroll
        for (int ct = 0; ct < 4; ct++) {
            const float c = acc2[rt][ct][i] + bv[ct];
            out[(size_t)(row0 + rl) * D_ + colv[ct]] = split_pack((c - mu) * rs * gv[ct] + bbv[ct]);
        }
    }
}

// ---------- lite MFMA global k-max, full-width blocks (grid 4096) ----------
__global__ void __launch_bounds__(256) k_dmax(
    const unsigned* __restrict__ kg, const unsigned* __restrict__ P2, int* __restrict__ slot)
{
    __shared__ __align__(16) ushort A2s[64 * 40];
    __shared__ __align__(16) ushort Ps[256 * 40];
    __shared__ float sred[4];
    const int t = threadIdx.x;
    const size_t row0 = (size_t)blockIdx.x * 64;
    {
        const int row = t >> 2, seg = t & 3;
        const unsigned* src = kg + (row0 + row) * DH_ + seg * 8;
        const uint4 f0 = *(const uint4*)src;
        const uint4 f1 = *(const uint4*)(src + 4);
        *(uint4*)&A2s[row * 40 + seg * 8] =
            make_uint4(hpair(f0.x, f0.y), hpair(f0.z, f0.w), hpair(f1.x, f1.y), hpair(f1.z, f1.w));
    }
    {
        const int col = t;
        const unsigned* src = P2 + (size_t)col * DH_;
#pragma unroll
        for (int hf = 0; hf < 2; hf++) {
            const uint4 g0 = *(const uint4*)(src + hf * 16);
            const uint4 g1 = *(const uint4*)(src + hf * 16 + 4);
            const uint4 g2 = *(const uint4*)(src + hf * 16 + 8);
            const uint4 g3 = *(const uint4*)(src + hf * 16 + 12);
            *(uint4*)&Ps[col * 40 + hf * 16] =
                make_uint4(hpair(g0.x, g0.y), hpair(g0.z, g0.w), hpair(g1.x, g1.y), hpair(g1.z, g1.w));
            *(uint4*)&Ps[col * 40 + hf * 16 + 8] =
                make_uint4(hpair(g2.x, g2.y), hpair(g2.z, g2.w), hpair(g3.x, g3.y), hpair(g3.z, g3.w));
        }
    }
    __syncthreads();
    const int w = t >> 6, lane = t & 63, quad = lane >> 4, l16 = lane & 15;
    floatx4 acc[4][4];
#pragma unroll
    for (int rt = 0; rt < 4; rt++)
#pragma unroll
        for (int ct = 0; ct < 4; ct++) acc[rt][ct] = (floatx4){0.f, 0.f, 0.f, 0.f};
    short8 af[4], bf[4];
#pragma unroll
    for (int rt = 0; rt < 4; rt++)
        af[rt] = *(const short8*)&A2s[(rt * 16 + l16) * 40 + quad * 8];
#pragma unroll
    for (int ct = 0; ct < 4; ct++)
        bf[ct] = *(const short8*)&Ps[((w * 4 + ct) * 16 + l16) * 40 + quad * 8];
#pragma unroll
    for (int rt = 0; rt < 4; rt++)
#pragma unroll
        for (int ct = 0; ct < 4; ct++)
            acc[rt][ct] = __builtin_amdgcn_mfma_f32_16x16x32_bf16(af[rt], bf[ct], acc[rt][ct], 0, 0, 0);
    float mx = -INFINITY;
#pragma unroll
    for (int rt = 0; rt < 4; rt++)
#pragma unroll
        for (int ct = 0; ct < 4; ct++)
#pragma unroll
            for (int i = 0; i < 4; i++) mx = fmaxf(mx, acc[rt][ct][i]);
#pragma unroll
    for (int o = 32; o > 0; o >>= 1) mx = fmaxf(mx, __shfl_xor(mx, o, 64));
    if (lane == 0) sred[w] = mx;
    __syncthreads();
    if (t == 0) {
        const float m4 = fmaxf(fmaxf(sred[0], sred[1]), fmaxf(sred[2], sred[3]))
                       * 0.42044820762685725f;
        const int i = __float_as_int(m4);
        atomicMax(slot, (i >= 0) ? i : (i ^ 0x7fffffff));
    }
}

// ---------- performer attention v5d (unchanged) ----------
__global__ void __launch_bounds__(1024) k_attn2(
    const unsigned* __restrict__ qg, const unsigned* __restrict__ kg, const unsigned* __restrict__ vg,
    const unsigned* __restrict__ P2, const int* __restrict__ slot,
    unsigned* __restrict__ outp)
{
    extern __shared__ char smem[];
    ushort* sAh   = (ushort*)(smem);            // [128][40] K h-plane
    ushort* sAl   = (ushort*)(smem + 10240);    // [128][40] K l-plane
    ushort* sBh   = (ushort*)(smem + 20480);    // [64][40] P-quarter h
    ushort* sBl   = (ushort*)(smem + 25600);    // [64][40] P-quarter l
    ushort* kpS   = (ushort*)(smem + 30720);    // [64][136] kp bf16 compact; oRed alias
    ushort* sV    = (ushort*)(smem + 48128);    // [32][136] v bf16 compact
    ushort* sCtx  = (ushort*)(smem + 56832);    // [32][264] ctx bf16 compact
    float* sdk    = (float*)(smem + 73728);     // [128] (+kmax fold)
    float* sdq    = (float*)(smem + 74240);     // [128]
    float* smaxP  = (float*)(smem + 74752);     // [2][128]
    float* sdenP  = smaxP;                      // ALIAS (smaxP dead after dmq)
    float* sksum  = (float*)(smem + 75776);     // [256]
    float* sksP   = (float*)(smem + 76800);     // [16][32]

    const int bh = blockIdx.x;
    const int b = bh >> 3, hh = bh & 7;
    const int t = threadIdx.x;
    const int w = t >> 6, lane = t & 63, quad = lane >> 4, l16 = lane & 15;
    const int wg = w & 7, wh = w >> 3;
    const int nq = wg * 16 + l16;
    const unsigned* kb = kg + (size_t)bh * S_ * DH_;
    const unsigned* qb = qg + (size_t)bh * S_ * DH_;
    const unsigned* vb = vg + (size_t)bh * S_ * DH_;
    const float nrm = 0.42044820762685725f;
    const float diagc = 0.5f * nrm * nrm;
    const float ratio = 0.0625f;

    union U8 { uint4 u; short8 s; };
    union U4 { uint2 u; bfx4 s; };

    float kmaxv;
    { const int iv = *slot; kmaxv = __int_as_float((iv >= 0) ? iv : (iv ^ 0x7fffffff)); }

    short8 qfh, qfl;
    {
        const unsigned* qrow = qb + (size_t)nq * DH_ + quad * 8;
        const uint4 q0 = *(const uint4*)qrow;
        const uint4 q1 = *(const uint4*)(qrow + 4);
        U8 th; th.u = make_uint4(hpair(q0.x, q0.y), hpair(q0.z, q0.w), hpair(q1.x, q1.y), hpair(q1.z, q1.w));
        U8 tl; tl.u = make_uint4(lpair(q0.x, q0.y), lpair(q0.z, q0.w), lpair(q1.x, q1.y), lpair(q1.z, q1.w));
        qfh = th.s; qfl = tl.s;
    }

    if (t < 512) {
        const int row = t >> 2, seg = t & 3;
        const unsigned* src = kb + row * DH_ + seg * 8;
        const uint4 f0 = *(const uint4*)&src[0];
        const uint4 f1 = *(const uint4*)&src[4];
        *(uint4*)&sAh[row * 40 + seg * 8] =
            make_uint4(hpair(f0.x, f0.y), hpair(f0.z, f0.w), hpair(f1.x, f1.y), hpair(f1.z, f1.w));
        *(uint4*)&sAl[row * 40 + seg * 8] =
            make_uint4(lpair(f0.x, f0.y), lpair(f0.z, f0.w), lpair(f1.x, f1.y), lpair(f1.z, f1.w));
    } else {
        const int tt2 = t - 512;
        const int n = tt2 & 127, d0 = (tt2 >> 7) * 8;
        const unsigned* src = vb + n * DH_ + d0;
        const uint4 f0 = *(const uint4*)&src[0];
        const uint4 f1 = *(const uint4*)&src[4];
        const unsigned uu[8] = {f0.x, f0.y, f0.z, f0.w, f1.x, f1.y, f1.z, f1.w};
#pragma unroll
        for (int j = 0; j < 8; j++)
            sV[(d0 + j) * 136 + n] = (ushort)(uu[j] & 0xffffu);
    }
    if (t < 128) {
        float s = 0.f, s2 = 0.f;
#pragma unroll
        for (int d4 = 0; d4 < DH_ / 4; d4++) {
            const uint4 kk = *(const uint4*)&kb[t * DH_ + d4 * 4];
            const float k0 = rec(kk.x), k1 = rec(kk.y), k2 = rec(kk.z), k3 = rec(kk.w);
            s += k0 * k0 + k1 * k1 + k2 * k2 + k3 * k3;
            const uint4 qq = *(const uint4*)&qb[t * DH_ + d4 * 4];
            const float q0 = rec(qq.x), q1 = rec(qq.y), q2 = rec(qq.z), q3 = rec(qq.w);
            s2 += q0 * q0 + q1 * q1 + q2 * q2 + q3 * q3;
        }
        sdk[t] = s * diagc + kmaxv;
        sdq[t] = s2 * diagc;
    }
    __syncthreads();

    floatx4 adq[2][4];
#pragma unroll
    for (int j = 0; j < 2; j++)
#pragma unroll
        for (int mtl = 0; mtl < 4; mtl++) adq[j][mtl] = (floatx4){0.f, 0.f, 0.f, 0.f};

#pragma unroll
    for (int qd = 0; qd < 4; qd++) {
        {
            const int col = t >> 4, ch2 = t & 15;
            const unsigned* src = P2 + (size_t)(qd * 64 + col) * DH_ + ch2 * 2;
            const unsigned u0 = src[0], u1 = src[1];
            ((unsigned*)sBh)[col * 20 + ch2] = hpair(u0, u1);
            ((unsigned*)sBl)[col * 20 + ch2] = lpair(u0, u1);
        }
        __syncthreads();
        floatx4 acc[2];
        acc[0] = (floatx4){0.f, 0.f, 0.f, 0.f};
        acc[1] = (floatx4){0.f, 0.f, 0.f, 0.f};
        {
            const short8 afh = *(const short8*)&sAh[nq * 40 + quad * 8];
            const short8 afl = *(const short8*)&sAl[nq * 40 + quad * 8];
#pragma unroll
            for (int ctl = 0; ctl < 2; ctl++) {
                const int mrow = ((2 * wh + ctl) * 16 + l16) * 40 + quad * 8;
                const short8 bfh = *(const short8*)&sBh[mrow];
                const short8 bfl = *(const short8*)&sBl[mrow];
                acc[ctl] = __builtin_amdgcn_mfma_f32_16x16x32_bf16(afh, bfh, acc[ctl], 0, 0, 0);
                acc[ctl] = __builtin_amdgcn_mfma_f32_16x16x32_bf16(afh, bfl, acc[ctl], 0, 0, 0);
                acc[ctl] = __builtin_amdgcn_mfma_f32_16x16x32_bf16(afl, bfh, acc[ctl], 0, 0, 0);
            }
        }
        float kc[2];
#pragma unroll
        for (int ctl = 0; ctl < 2; ctl++) {
            float kcl = 0.f;
            ushort kh[4];
#pragma unroll
            for (int i = 0; i < 4; i++) {
                const int n = wg * 16 + quad * 4 + i;
                const float kp = ratio * (__expf(acc[ctl][i] * nrm - sdk[n]) + 1e-4f);
                kh[i] = bf16_rn(kp);
                kcl += __uint_as_float((unsigned)kh[i] << 16);
            }
            *(uint2*)&kpS[((2 * wh + ctl) * 16 + l16) * 136 + wg * 16 + quad * 4] =
                make_uint2((unsigned)kh[0] | ((unsigned)kh[1] << 16),
                           (unsigned)kh[2] | ((unsigned)kh[3] << 16));
            kc[ctl] = kcl;
        }
#pragma unroll
        for (int ctl = 0; ctl < 2; ctl++) {
            kc[ctl] += __shfl_xor(kc[ctl], 16, 64);
            kc[ctl] += __shfl_xor(kc[ctl], 32, 64);
        }
        if (quad == 0) {
            sksP[w * 32 + l16] = kc[0];
            sksP[w * 32 + 16 + l16] = kc[1];
        }
        __syncthreads();
        const int qown = (qd & 1) ^ 1;
        if (wh == qown) {
            const int aidx2 = qd >> 1;
#pragma unroll
            for (int mtl = 0; mtl < 4; mtl++) {
                const int prow = (mtl * 16 + l16) * 40 + quad * 8;
                const short8 aPh = *(const short8*)&sBh[prow];
                const short8 aPl = *(const short8*)&sBl[prow];
                adq[aidx2][mtl] = __builtin_amdgcn_mfma_f32_16x16x32_bf16(aPh, qfh, adq[aidx2][mtl], 0, 0, 0);
                adq[aidx2][mtl] = __builtin_amdgcn_mfma_f32_16x16x32_bf16(aPh, qfl, adq[aidx2][mtl], 0, 0, 0);
                adq[aidx2][mtl] = __builtin_amdgcn_mfma_f32_16x16x32_bf16(aPl, qfh, adq[aidx2][mtl], 0, 0, 0);
            }
        } else {
            const int mt = wg & 3, dt = wg >> 2;
            floatx4 cacc = (floatx4){0.f, 0.f, 0.f, 0.f};
#pragma unroll
            for (int ks = 0; ks < 4; ks++) {
                const short8 a = *(const short8*)&kpS[(mt * 16 + l16) * 136 + ks * 32 + quad * 8];
                const short8 bvv = *(const short8*)&sV[(dt * 16 + l16) * 136 + ks * 32 + quad * 8];
                cacc = __builtin_amdgcn_mfma_f32_16x16x32_bf16(a, bvv, cacc, 0, 0, 0);
            }
            ushort ch[4];
#pragma unroll
            for (int i = 0; i < 4; i++) ch[i] = bf16_rn(cacc[i]);
            *(uint2*)&sCtx[(dt * 16 + l16) * 264 + qd * 64 + mt * 16 + quad * 4] =
                make_uint2((unsigned)ch[0] | ((unsigned)ch[1] << 16),
                           (unsigned)ch[2] | ((unsigned)ch[3] << 16));
        }
        if (t < 64) {
            float s = 0.f;
#pragma unroll
            for (int wg2 = 0; wg2 < 8; wg2++)
                s += sksP[((t >> 5) * 8 + wg2) * 32 + (t & 31)];
            sksum[qd * 64 + t] = s;
        }
        __syncthreads();
    }

    {
        float mxn = -INFINITY;
#pragma unroll
        for (int j = 0; j < 2; j++)
#pragma unroll
            for (int mtl = 0; mtl < 4; mtl++)
#pragma unroll
                for (int i = 0; i < 4; i++) mxn = fmaxf(mxn, adq[j][mtl][i]);
        mxn = fmaxf(mxn, __shfl_xor(mxn, 16, 64));
        mxn = fmaxf(mxn, __shfl_xor(mxn, 32, 64));
        if (quad == 0) smaxP[wh * 128 + nq] = mxn;
    }
    __syncthreads();
    const float dmq = sdq[nq] + fmaxf(smaxP[nq], smaxP[128 + nq]) * nrm;

    floatx4 oT[2];
    oT[0] = (floatx4){0.f, 0.f, 0.f, 0.f};
    oT[1] = (floatx4){0.f, 0.f, 0.f, 0.f};
    float dp = 0.f;
#pragma unroll
    for (int j = 0; j < 2; j++) {
        const int qdo = 2 * j + (wh ^ 1);
#pragma unroll
        for (int mtl = 0; mtl < 4; mtl++) {
            ushort qh[4];
#pragma unroll
            for (int i = 0; i < 4; i++) {
                const float qp = ratio * (__expf(adq[j][mtl][i] * nrm - dmq) + 1e-4f);
                qh[i] = bf16_rn(qp);
                dp += __uint_as_float((unsigned)qh[i] << 16)
                    * sksum[qdo * 64 + mtl * 16 + quad * 4 + i];
            }
            U4 tb;
            tb.u = make_uint2((unsigned)qh[0] | ((unsigned)qh[1] << 16),
                              (unsigned)qh[2] | ((unsigned)qh[3] << 16));
#pragma unroll
            for (int dt = 0; dt < 2; dt++) {
                U4 ta;
                ta.u = *(const uint2*)&sCtx[(dt * 16 + l16) * 264 + qdo * 64 + mtl * 16 + quad * 4];
                oT[dt] = __builtin_amdgcn_mfma_f32_16x16x16bf16_1k(ta.s, tb.s, oT[dt], 0, 0, 0);
            }
        }
    }
    dp += __shfl_xor(dp, 16, 64);
    dp += __shfl_xor(dp, 32, 64);
    __syncthreads();   // all smaxP reads (dmq) done before sdenP overlay writes
    if (quad == 0) sdenP[wh * 128 + nq] = dp;

    float* oRed = (float*)kpS;
    if (wh == 1) {
#pragma unroll
        for (int dt = 0; dt < 2; dt++)
            *(floatx4*)&oRed[((wg * 2 + dt) * 64 + lane) * 4] = oT[dt];
    }
    __syncthreads();
    if (wh == 0) {
        const float inv = 1.0f / (sdenP[nq] + sdenP[128 + nq]);
#pragma unroll
        for (int dt = 0; dt < 2; dt++) {
            const floatx4 o2 = *(const floatx4*)&oRed[((wg * 2 + dt) * 64 + lane) * 4];
            const unsigned r0 = split_pack((oT[dt][0] + o2[0]) * inv);
            const unsigned r1 = split_pack((oT[dt][1] + o2[1]) * inv);
            const unsigned r2 = split_pack((oT[dt][2] + o2[2]) * inv);
            const unsigned r3 = split_pack((oT[dt][3] + o2[3]) * inv);
            *(uint4*)&outp[((size_t)b * S_ + nq) * D_ + hh * DH_ + dt * 16 + quad * 4] =
                make_uint4(r0, r1, r2, r3);
        }
    }
}

// ---------- classification head (packed input) ----------
__global__ void __launch_bounds__(256) k_head(
    const unsigned* __restrict__ hfin, const float* __restrict__ h1w, const float* __restrict__ h1b,
    const float* __restrict__ h2w, const float* __restrict__ h2b,
    const float* __restrict__ ow, const float* __restrict__ ob, float* __restrict__ outp)
{
    __shared__ float c0[D_];
    __shared__ float c1[2 * HID_];
    __shared__ float sred[4];
    const int t = threadIdx.x;
    const int b = blockIdx.x;
    c0[t] = rec(hfin[(size_t)b * S_ * D_ + t]);
    __syncthreads();
#pragma unroll
    for (int half = 0; half < 2; half++) {
        const int j = half * 256 + t;
        float a = h1b[j];
        const float* w = h1w + (size_t)j * D_;
        for (int d = 0; d < D_; d += 4) {
            const float4 w4 = *(const float4*)&w[d];
            const float4 x4 = *(const float4*)&c0[d];
            a += x4.x * w4.x + x4.y * w4.y + x4.z * w4.z + x4.w * w4.w;
        }
        c1[j] = (a >= 0.f) ? a : 0.2f * a;
    }
    __syncthreads();
    float a2 = h2b[t];
    const float* w2 = h2w + (size_t)t * (2 * HID_);
    for (int j = 0; j < 2 * HID_; j += 4) {
        const float4 w4 = *(const float4*)&w2[j];
        const float4 x4 = *(const float4*)&c1[j];
        a2 += x4.x * w4.x + x4.y * w4.y + x4.z * w4.z + x4.w * w4.w;
    }
    const float c2 = (a2 >= 0.f) ? a2 : 0.2f * a2;
    const float s = blk_sum(c2 * ow[t], sred);
    if (t == 0) outp[b] = s + ob[0];
}

extern "C" void kernel_launch(void* const* d_in, const int* in_sizes, int n_in,
                              void* d_out, int out_size, void* d_ws, size_t ws_size,
                              hipStream_t stream)
{
    const float* x     = (const float*)d_in[0];
    const int*   mask  = (const int*)d_in[1];
    const float* emb_w = (const float*)d_in[2];
    const float* emb_b = (const float*)d_in[3];
    const float* Wq    = (const float*)d_in[4];
    const float* bq    = (const float*)d_in[5];
    const float* Wk    = (const float*)d_in[6];
    const float* bk    = (const float*)d_in[7];
    const float* Wv    = (const float*)d_in[8];
    const float* bv    = (const float*)d_in[9];
    const float* Wo    = (const float*)d_in[10];
    const float* bo    = (const float*)d_in[11];
    const float* proj  = (const float*)d_in[12];
    const float* n1w   = (const float*)d_in[13];
    const float* n1b   = (const float*)d_in[14];
    const float* n2w   = (const float*)d_in[15];
    const float* n2b   = (const float*)d_in[16];
    const float* f1w   = (const float*)d_in[17];
    const float* f1b   = (const float*)d_in[18];
    const float* f2w   = (const float*)d_in[19];
    const float* f2b   = (const float*)d_in[20];
    const float* h1w   = (const float*)d_in[21];
    const float* h1b   = (const float*)d_in[22];
    const float* h2w   = (const float*)d_in[23];
    const float* h2b   = (const float*)d_in[24];
    const float* ow    = (const float*)d_in[25];
    const float* ob    = (const float*)d_in[26];

    const size_t BSD = (size_t)B_ * S_ * D_;
    unsigned* A = (unsigned*)d_ws;                 // packed activations
    unsigned* Q = A + BSD;
    unsigned* K = Q + BSD;
    unsigned* V = K + BSD;
    const size_t WMU = 65536;                      // ushorts per matrix plane (256x256)
    ushort* WH = (ushort*)(V + BSD);               // 6 x L x 65536 ushorts (h planes)
    ushort* WL = WH + 6 * L_ * WMU;                // 6 x L x 65536 ushorts (l planes)
    unsigned* P2 = (unsigned*)(WL + 6 * L_ * WMU); // compact split proj: L x 256 x 32 uints
    int* slots = (int*)(P2 + (size_t)L_ * M_ * DH_);

    // fused prep: weights + proj + reset + embedding (blocks 801..8992)
    k_prep<<<801 + 8192, 256, 0, stream>>>(Wq, Wk, Wv, Wo, f1w, f2w, proj, WH, WL, P2, slots,
                                           x, emb_w, emb_b, A);

    const int QB = B_ * S_ / 64;               // 512 blocks for single-pass QKV
    const int DB = B_ * H_ * S_ / 64;          // 4096 blocks for k_dmax
    const size_t ATTN_LDS = 78848;             // 77 KB dynamic LDS

    for (int l = 0; l < L_; l++) {
        const unsigned* P2l = P2 + (size_t)l * M_ * DH_;
        k_gemm_qkv<<<QB, 512, 0, stream>>>(A, WH, WL, l, bq + l * D_, bk + l * D_, bv + l * D_, mask, Q, K, V);
        k_dmax<<<DB, 256, 0, stream>>>(K, P2l, slots + l);
        k_attn2<<<B_ * H_, 1024, ATTN_LDS, stream>>>(Q, K, V, P2l, slots + l, A);
        k_wofn<<<B_ * S_ / 64, 512, 0, stream>>>(A,
            WH + (3 * L_ + l) * WMU, WL + (3 * L_ + l) * WMU,
            WH + (4 * L_ + l) * WMU, WL + (4 * L_ + l) * WMU,
            WH + (5 * L_ + l) * WMU, WL + (5 * L_ + l) * WMU,
            bo + l * D_, n1w + l * D_, n1b + l * D_,
            f1b + l * HID_, f2b + l * D_, n2w + l * D_, n2b + l * D_, A);
    }
    k_head<<<B_, 256, 0, stream>>>(A, h1w, h1b, h2w, h2b, ow, ob, (float*)d_out);
}

// Round 19
// 1145.257 us; speedup vs baseline: 1.0242x; 1.0242x over previous
//
#include <hip/hip_runtime.h>
#include <math.h>

#define B_ 256
#define N_ 127
#define S_ 128
#define NDIM_ 3
#define D_ 256
#define H_ 8
#define DH_ 32
#define M_ 256
#define HID_ 256
#define L_ 4
#define LOG2E 1.44269504088896340736f

typedef __attribute__((ext_vector_type(8))) short short8;
typedef __attribute__((ext_vector_type(4))) short bfx4;
typedef __attribute__((ext_vector_type(4))) float floatx4;

// ---------- bf16 split helpers ----------
__device__ __forceinline__ ushort bf16_rn(float x) {
    unsigned u = __float_as_uint(x);
    u = (u + 0x7fffu + ((u >> 16) & 1u)) >> 16;
    return (ushort)u;
}
__device__ __forceinline__ unsigned split_pack(float x) {
    const ushort h = bf16_rn(x);
    const float r = x - __uint_as_float(((unsigned)h) << 16);
    const ushort l = bf16_rn(r);
    return (unsigned)h | ((unsigned)l << 16);
}
__device__ __forceinline__ float rec(unsigned u) {
    return __uint_as_float(u << 16) + __uint_as_float(u & 0xffff0000u);
}
__device__ __forceinline__ unsigned hpair(unsigned u0, unsigned u1) {
    return (u0 & 0xffffu) | (u1 << 16);
}
__device__ __forceinline__ unsigned lpair(unsigned u0, unsigned u1) {
    return (u0 >> 16) | (u1 & 0xffff0000u);
}

// ---------- block reductions ----------
__device__ __forceinline__ float blk_sum(float v, float* sred) {
#pragma unroll
    for (int o = 32; o > 0; o >>= 1) v += __shfl_xor(v, o, 64);
    if ((threadIdx.x & 63) == 0) sred[threadIdx.x >> 6] = v;
    __syncthreads();
    v = sred[0] + sred[1] + sred[2] + sred[3];
    __syncthreads();
    return v;
}

// ---------- fused prep: weight planes + proj conv + slot reset + embedding ----------
__global__ void __launch_bounds__(256) k_prep(
    const float* __restrict__ Wq, const float* __restrict__ Wk, const float* __restrict__ Wv,
    const float* __restrict__ Wo, const float* __restrict__ f1w, const float* __restrict__ f2w,
    const float* __restrict__ proj, ushort* __restrict__ WH, ushort* __restrict__ WL,
    unsigned* __restrict__ P2, int* __restrict__ slots,
    const float* __restrict__ x, const float* __restrict__ ew, const float* __restrict__ eb,
    unsigned* __restrict__ Aout)
{
    const int bid = blockIdx.x;
    if (bid < 768) {
        const int tensor = bid / 128;
        const int tid = (bid & 127) * 256 + threadIdx.x;
        const float* src = tensor == 0 ? Wq : tensor == 1 ? Wk : tensor == 2 ? Wv
                         : tensor == 3 ? Wo : tensor == 4 ? f1w : f2w;
        ushort* dh = WH + (size_t)tensor * L_ * 65536;
        ushort* dl = WL + (size_t)tensor * L_ * 65536;
        const int l = tid >> 13;
        const int col = (tid >> 5) & 255, kc = tid & 31;
        const float* sp = src + ((size_t)l << 16) + col * 256 + kc * 8;
        float v[8];
        *(float4*)&v[0] = *(const float4*)sp;
        *(float4*)&v[4] = *(const float4*)(sp + 4);
        unsigned hu[4], lu[4];
#pragma unroll
        for (int i = 0; i < 4; i++) {
            const unsigned u0 = split_pack(v[2 * i]);
            const unsigned u1 = split_pack(v[2 * i + 1]);
            hu[i] = hpair(u0, u1);
            lu[i] = lpair(u0, u1);
        }
        const size_t off = ((size_t)l << 16) + ((size_t)(kc * 256 + col)) * 8;
        *(uint4*)&dh[off] = make_uint4(hu[0], hu[1], hu[2], hu[3]);
        *(uint4*)&dl[off] = make_uint4(lu[0], lu[1], lu[2], lu[3]);
    } else if (bid < 800) {
        const int idx = ((bid - 768) * 256 + threadIdx.x) * 4;
        const float4 w4 = *(const float4*)&proj[idx];
        const float v[4] = {w4.x, w4.y, w4.z, w4.w};
        unsigned u[4];
#pragma unroll
        for (int i = 0; i < 4; i++) u[i] = split_pack(v[i]);
        *(uint4*)&P2[idx] = make_uint4(u[0], u[1], u[2], u[3]);
    } else if (bid == 800) {
        if (threadIdx.x < 4) {
            const int i = __float_as_int(-INFINITY);
            slots[threadIdx.x] = (i >= 0) ? i : (i ^ 0x7fffffff);
        }
    } else {
        const int idx4 = (bid - 801) * 256 + threadIdx.x;
        const int d0 = (idx4 & 63) * 4;
        const int n = (idx4 >> 6) & (S_ - 1);
        const int b = idx4 >> 13;
        unsigned r[4] = {0u, 0u, 0u, 0u};
        if (n > 0) {
            const float* xr = x + ((size_t)b * N_ + (n - 1)) * NDIM_;
            const float x0 = xr[0], x1 = xr[1], x2 = xr[2];
#pragma unroll
            for (int j = 0; j < 4; j++) {
                const int d = d0 + j;
                const float val = eb[d] + x0 * ew[d * 3 + 0] + x1 * ew[d * 3 + 1] + x2 * ew[d * 3 + 2];
                r[j] = split_pack(val);
            }
        }
        *(uint4*)&Aout[(size_t)idx4 * 4] = make_uint4(r[0], r[1], r[2], r[3]);
    }
}

// ---------- fused Q/K/V GEMM, 128-row tiles (grid 768) — R17 proven-best ----------
__global__ void __launch_bounds__(512, 2) k_gemm_qkv(
    const unsigned* __restrict__ Ap, const ushort* __restrict__ WHb,
    const ushort* __restrict__ WLb, const int l,
    const float* __restrict__ bq, const float* __restrict__ bk, const float* __restrict__ bv_,
    const int* __restrict__ mask,
    unsigned* __restrict__ Qo, unsigned* __restrict__ Ko, unsigned* __restrict__ Vo)
{
    __shared__ ushort sAh[2][4160];
    __shared__ ushort sAl[2][4160];
    const int t = threadIdx.x;
    const int w = t >> 6, lane = t & 63;
    const int quad = lane >> 4, l16 = lane & 15;
    const int rowbase = 64 * (w >> 2), colbase = 64 * (w & 3);
    const int which = blockIdx.x >> 8;
    const int row0 = (blockIdx.x & 255) * 128;
    const ushort* WH = WHb + ((size_t)(which * L_ + l)) * 65536;
    const ushort* WL = WLb + ((size_t)(which * L_ + l)) * 65536;
    const float* bias = which == 0 ? bq : which == 1 ? bk : bv_;
    unsigned* out = which == 0 ? Qo : which == 1 ? Ko : Vo;

    floatx4 acc[4][4];
#pragma unroll
    for (int rt = 0; rt < 4; rt++)
#pragma unroll
        for (int ct = 0; ct < 4; ct++) acc[rt][ct] = (floatx4){0.f, 0.f, 0.f, 0.f};

    const int arow = t >> 2, achunk = t & 3;
    const unsigned* AG = Ap + (size_t)(row0 + arow) * D_ + achunk * 8;
    const int aidx = achunk * 1040 + arow * 8;

    {
        const uint4 a0 = *(const uint4*)AG;
        const uint4 a1 = *(const uint4*)(AG + 4);
        *(uint4*)&sAh[0][aidx] = make_uint4(hpair(a0.x, a0.y), hpair(a0.z, a0.w),
                                            hpair(a1.x, a1.y), hpair(a1.z, a1.w));
        *(uint4*)&sAl[0][aidx] = make_uint4(lpair(a0.x, a0.y), lpair(a0.z, a0.w),
                                            lpair(a1.x, a1.y), lpair(a1.z, a1.w));
    }
    __syncthreads();

    for (int s = 0; s < 8; s++) {
        const int p = s & 1;
        uint4 a0n, a1n;
        if (s + 1 < 8) {
            a0n = *(const uint4*)(AG + (s + 1) * 32);
            a1n = *(const uint4*)(AG + (s + 1) * 32 + 4);
        }
        const size_t wbase = ((size_t)((s * 4 + quad) * 256 + colbase + l16)) * 8;
        const ushort* WHf = WH + wbase;
        const ushort* WLf = WL + wbase;
        short8 ah[4], al[4], wh[4], wl[4];
#pragma unroll
        for (int ct = 0; ct < 4; ct++) {
            wh[ct] = *(const short8*)&WHf[ct * 128];
            wl[ct] = *(const short8*)&WLf[ct * 128];
        }
#pragma unroll
        for (int rt = 0; rt < 4; rt++) {
            const int ai = quad * 1040 + (rowbase + 16 * rt + l16) * 8;
            ah[rt] = *(const short8*)&sAh[p][ai];
            al[rt] = *(const short8*)&sAl[p][ai];
        }
#pragma unroll
        for (int rt = 0; rt < 4; rt++)
#pragma unroll
            for (int ct = 0; ct < 4; ct++) {
                acc[rt][ct] = __builtin_amdgcn_mfma_f32_16x16x32_bf16(ah[rt], wh[ct], acc[rt][ct], 0, 0, 0);
                acc[rt][ct] = __builtin_amdgcn_mfma_f32_16x16x32_bf16(ah[rt], wl[ct], acc[rt][ct], 0, 0, 0);
                acc[rt][ct] = __builtin_amdgcn_mfma_f32_16x16x32_bf16(al[rt], wh[ct], acc[rt][ct], 0, 0, 0);
            }
        if (s + 1 < 8) {
            *(uint4*)&sAh[p ^ 1][aidx] = make_uint4(hpair(a0n.x, a0n.y), hpair(a0n.z, a0n.w),
                                                    hpair(a1n.x, a1n.y), hpair(a1n.z, a1n.w));
            *(uint4*)&sAl[p ^ 1][aidx] = make_uint4(lpair(a0n.x, a0n.y), lpair(a0n.z, a0n.w),
                                                    lpair(a1n.x, a1n.y), lpair(a1n.z, a1n.w));
        }
        __syncthreads();
    }

    int colv[4]; float bv[4];
#pragma unroll
    for (int ct = 0; ct < 4; ct++) { colv[ct] = colbase + 16 * ct + l16; bv[ct] = bias[colv[ct]]; }

    const int b = row0 >> 7;
#pragma unroll
    for (int rt = 0; rt < 4; rt++)
#pragma unroll
    for (int i = 0; i < 4; i++) {
        const int rl = rowbase + 16 * rt + quad * 4 + i;
        const int n = (row0 + rl) & (S_ - 1);
        float keep = 1.f;
        if (which == 2) keep = (n == 0) ? 1.f : (mask[b * N_ + n - 1] ? 0.f : 1.f);
#pragma unroll
        for (int ct = 0; ct < 4; ct++) {
            float c = acc[rt][ct][i] + bv[ct];
            c *= keep;
            const int col = colv[ct];
            out[(((size_t)b * H_ + (col >> 5)) * S_ + n) * DH_ + (col & 31)] = split_pack(c);
        }
    }
}

// ---------- fused Wo+LN1+FFN+LN2 mega-kernel (64-row blocks, grid 512) ----------
__global__ void __launch_bounds__(512, 2) k_wofn(
    const unsigned* __restrict__ Ap,
    const ushort* __restrict__ WoH, const ushort* __restrict__ WoL,
    const ushort* __restrict__ W1H, const ushort* __restrict__ W1L,
    const ushort* __restrict__ W2H, const ushort* __restrict__ W2L,
    const float* __restrict__ bo, const float* __restrict__ n1w, const float* __restrict__ n1b,
    const float* __restrict__ b1, const float* __restrict__ b2,
    const float* __restrict__ g2w, const float* __restrict__ g2b,
    unsigned* __restrict__ out)
{
    __shared__ char smemc[67584];
    ushort* Th  = (ushort*)smemc;              // [64][264] T planes; later G1
    ushort* Tl  = (ushort*)(smemc + 33792);
    ushort* sTh = (ushort*)smemc;              // [2][2080] A staging (alias, dead first)
    ushort* sTl = (ushort*)(smemc + 8320);
    __shared__ float sredA[64][8], sredB[64][8];
    const int t = threadIdx.x;
    const int w = t >> 6, lane = t & 63;
    const int quad = lane >> 4, l16 = lane & 15;
    const int row0 = blockIdx.x * 64;

    // ---- stage 0: T^T = Wo^T x A^T ----
    floatx4 acc[2][4];
#pragma unroll
    for (int rt = 0; rt < 2; rt++)
#pragma unroll
        for (int ct = 0; ct < 4; ct++) acc[rt][ct] = (floatx4){0.f, 0.f, 0.f, 0.f};

    const int arow = t >> 3, akq = t & 7;
    const unsigned* AG = Ap + (size_t)(row0 + arow) * D_ + akq * 4;
    const int aidx = (akq >> 1) * 520 + arow * 8 + (akq & 1) * 4;

    {
        const uint4 a4 = *(const uint4*)AG;
        *(uint2*)&sTh[aidx] = make_uint2(hpair(a4.x, a4.y), hpair(a4.z, a4.w));
        *(uint2*)&sTl[aidx] = make_uint2(lpair(a4.x, a4.y), lpair(a4.z, a4.w));
    }
    __syncthreads();

    for (int s = 0; s < 8; s++) {
        const int p = s & 1;
        uint4 a_n;
        if (s + 1 < 8) a_n = *(const uint4*)(AG + (s + 1) * 32);
        const size_t wbase = ((size_t)((s * 4 + quad) * 256 + 32 * w + l16)) * 8;
        short8 fh[2], fl[2], th[4], tl[4];
#pragma unroll
        for (int rt = 0; rt < 2; rt++) {
            fh[rt] = *(const short8*)&WoH[wbase + rt * 128];
            fl[rt] = *(const short8*)&WoL[wbase + rt * 128];
        }
#pragma unroll
        for (int ct = 0; ct < 4; ct++) {
            const int ti = p * 2080 + quad * 520 + (16 * ct + l16) * 8;
            th[ct] = *(const short8*)&sTh[ti];
            tl[ct] = *(const short8*)&sTl[ti];
        }
#pragma unroll
        for (int rt = 0; rt < 2; rt++)
#pragma unroll
            for (int ct = 0; ct < 4; ct++) {
                acc[rt][ct] = __builtin_amdgcn_mfma_f32_16x16x32_bf16(fh[rt], th[ct], acc[rt][ct], 0, 0, 0);
                acc[rt][ct] = __builtin_amdgcn_mfma_f32_16x16x32_bf16(fl[rt], th[ct], acc[rt][ct], 0, 0, 0);
                acc[rt][ct] = __builtin_amdgcn_mfma_f32_16x16x32_bf16(fh[rt], tl[ct], acc[rt][ct], 0, 0, 0);
            }
        if (s + 1 < 8) {
            *(uint2*)&sTh[(p ^ 1) * 2080 + aidx] = make_uint2(hpair(a_n.x, a_n.y), hpair(a_n.z, a_n.w));
            *(uint2*)&sTl[(p ^ 1) * 2080 + aidx] = make_uint2(lpair(a_n.x, a_n.y), lpair(a_n.z, a_n.w));
        }
        __syncthreads();
    }

    // ---- LN1 epilogue on T^T layout ----
    {
        float bov[2][4];
#pragma unroll
        for (int rt = 0; rt < 2; rt++)
#pragma unroll
            for (int i = 0; i < 4; i++) bov[rt][i] = bo[32 * w + 16 * rt + quad * 4 + i];
        float ps[4], ps2[4];
#pragma unroll
        for (int ct = 0; ct < 4; ct++) { ps[ct] = 0.f; ps2[ct] = 0.f; }
#pragma unroll
        for (int rt = 0; rt < 2; rt++)
#pragma unroll
        for (int ct = 0; ct < 4; ct++)
#pragma unroll
        for (int i = 0; i < 4; i++) {
            const float c = acc[rt][ct][i] + bov[rt][i];
            acc[rt][ct][i] = c;
            ps[ct] += c; ps2[ct] += c * c;
        }
#pragma unroll
        for (int ct = 0; ct < 4; ct++) {
            ps[ct] += __shfl_xor(ps[ct], 16, 64);  ps[ct] += __shfl_xor(ps[ct], 32, 64);
            ps2[ct] += __shfl_xor(ps2[ct], 16, 64); ps2[ct] += __shfl_xor(ps2[ct], 32, 64);
        }
        if (quad == 0) {
#pragma unroll
            for (int ct = 0; ct < 4; ct++) {
                sredA[16 * ct + l16][w] = ps[ct];
                sredB[16 * ct + l16][w] = ps2[ct];
            }
        }
        __syncthreads();
        float mu[4], rs[4];
#pragma unroll
        for (int ct = 0; ct < 4; ct++) {
            const int n = 16 * ct + l16;
            float s = 0.f, s2 = 0.f;
#pragma unroll
            for (int k = 0; k < 8; k++) { s += sredA[n][k]; s2 += sredB[n][k]; }
            mu[ct] = s * (1.f / D_);
            rs[ct] = rsqrtf(s2 * (1.f / D_) - mu[ct] * mu[ct] + 1e-5f);
        }
        float gv1[2][4], bv1[2][4];
#pragma unroll
        for (int rt = 0; rt < 2; rt++)
#pragma unroll
            for (int i = 0; i < 4; i++) {
                const int c2 = 32 * w + 16 * rt + quad * 4 + i;
                gv1[rt][i] = n1w[c2];
                bv1[rt][i] = n1b[c2];
            }
#pragma unroll
        for (int ct = 0; ct < 4; ct++) {
            const int n = 16 * ct + l16;
#pragma unroll
            for (int rt = 0; rt < 2; rt++) {
                unsigned u[4];
#pragma unroll
                for (int i = 0; i < 4; i++) {
                    const float tv = (acc[rt][ct][i] - mu[ct]) * rs[ct] * gv1[rt][i] + bv1[rt][i];
                    u[i] = split_pack(tv);
                }
                const int base = n * 264 + 32 * w + 16 * rt + quad * 4;
                *(uint2*)&Th[base] = make_uint2(hpair(u[0], u[1]), hpair(u[2], u[3]));
                *(uint2*)&Tl[base] = make_uint2(lpair(u[0], u[1]), lpair(u[2], u[3]));
            }
        }
        __syncthreads();
    }

    // ---- stage 1: G1^T = f1w^T x T (barrier-free K-loop over resident T) ----
    floatx4 acc1[2][4];
#pragma unroll
    for (int rt = 0; rt < 2; rt++)
#pragma unroll
        for (int ct = 0; ct < 4; ct++) acc1[rt][ct] = (floatx4){0.f, 0.f, 0.f, 0.f};

    for (int s = 0; s < 8; s++) {
        const size_t wbase = ((size_t)((s * 4 + quad) * 256 + 32 * w + l16)) * 8;
        short8 fh[2], fl[2], th[4], tl[4];
#pragma unroll
        for (int rt = 0; rt < 2; rt++) {
            fh[rt] = *(const short8*)&W1H[wbase + rt * 128];
            fl[rt] = *(const short8*)&W1L[wbase + rt * 128];
        }
#pragma unroll
        for (int ct = 0; ct < 4; ct++) {
            const int ti = (16 * ct + l16) * 264 + s * 32 + quad * 8;
            th[ct] = *(const short8*)&Th[ti];
            tl[ct] = *(const short8*)&Tl[ti];
        }
#pragma unroll
        for (int rt = 0; rt < 2; rt++)
#pragma unroll
            for (int ct = 0; ct < 4; ct++) {
                acc1[rt][ct] = __builtin_amdgcn_mfma_f32_16x16x32_bf16(fh[rt], th[ct], acc1[rt][ct], 0, 0, 0);
                acc1[rt][ct] = __builtin_amdgcn_mfma_f32_16x16x32_bf16(fl[rt], th[ct], acc1[rt][ct], 0, 0, 0);
                acc1[rt][ct] = __builtin_amdgcn_mfma_f32_16x16x32_bf16(fh[rt], tl[ct], acc1[rt][ct], 0, 0, 0);
            }
    }
    __syncthreads();   // all T reads done before G1 overwrites the planes

    {
        float b1v[2][4];
#pragma unroll
        for (int rt = 0; rt < 2; rt++)
#pragma unroll
            for (int i = 0; i < 4; i++) b1v[rt][i] = b1[32 * w + 16 * rt + quad * 4 + i];
#pragma unroll
        for (int ct = 0; ct < 4; ct++) {
            const int n = 16 * ct + l16;
#pragma unroll
            for (int rt = 0; rt < 2; rt++) {
                unsigned u[4];
#pragma unroll
                for (int i = 0; i < 4; i++) {
                    float c = acc1[rt][ct][i] + b1v[rt][i];
                    c = (c >= 0.f) ? c : 0.2f * c;
                    u[i] = split_pack(c);
                }
                const int base = n * 264 + 32 * w + 16 * rt + quad * 4;
                *(uint2*)&Th[base] = make_uint2(hpair(u[0], u[1]), hpair(u[2], u[3]));
                *(uint2*)&Tl[base] = make_uint2(lpair(u[0], u[1]), lpair(u[2], u[3]));
            }
        }
        __syncthreads();
    }

    // ---- stage 2: out = G1 * f2w + LN2 ----
    const int rowbase = 32 * (w >> 2), colbase = 64 * (w & 3);
    const int colg = w & 3;
    floatx4 acc2[2][4];
#pragma unroll
    for (int rt = 0; rt < 2; rt++)
#pragma unroll
        for (int ct = 0; ct < 4; ct++) acc2[rt][ct] = (floatx4){0.f, 0.f, 0.f, 0.f};

    for (int ks = 0; ks < 8; ks++) {
        const size_t w2base = ((size_t)((ks * 4 + quad) * 256 + colbase + l16)) * 8;
        short8 ah[2], al[2], wh[4], wl[4];
#pragma unroll
        for (int ct = 0; ct < 4; ct++) {
            wh[ct] = *(const short8*)&W2H[w2base + ct * 128];
            wl[ct] = *(const short8*)&W2L[w2base + ct * 128];
        }
#pragma unroll
        for (int rt = 0; rt < 2; rt++) {
            const int gi = (rowbase + 16 * rt + l16) * 264 + ks * 32 + quad * 8;
            ah[rt] = *(const short8*)&Th[gi];
            al[rt] = *(const short8*)&Tl[gi];
        }
#pragma unroll
        for (int rt = 0; rt < 2; rt++)
#pragma unroll
            for (int ct = 0; ct < 4; ct++) {
                acc2[rt][ct] = __builtin_amdgcn_mfma_f32_16x16x32_bf16(ah[rt], wh[ct], acc2[rt][ct], 0, 0, 0);
                acc2[rt][ct] = __builtin_amdgcn_mfma_f32_16x16x32_bf16(ah[rt], wl[ct], acc2[rt][ct], 0, 0, 0);
                acc2[rt][ct] = __builtin_amdgcn_mfma_f32_16x16x32_bf16(al[rt], wh[ct], acc2[rt][ct], 0, 0, 0);
            }
    }
    __syncthreads();

    int colv[4]; float bv[4], gv[4], bbv[4];
#pragma unroll
    for (int ct = 0; ct < 4; ct++) {
        colv[ct] = colbase + 16 * ct + l16;
        bv[ct] = b2[colv[ct]];
        gv[ct] = g2w[colv[ct]];
        bbv[ct] = g2b[colv[ct]];
    }
#pragma unroll
    for (int rt = 0; rt < 2; rt++)
#pragma unroll
    for (int i = 0; i < 4; i++) {
        const int rl = rowbase + 16 * rt + quad * 4 + i;
        float s = 0.f, s2 = 0.f;
#pragma unroll
        for (int ct = 0; ct < 4; ct++) {
            const float c = acc2[rt][ct][i] + bv[ct];
            s += c; s2 += c * c;
        }
#pragma unroll
        for (int o = 8; o > 0; o >>= 1) { s += __shfl_xor(s, o, 64); s2 += __shfl_xor(s2, o, 64); }
        if (l16 == 0) { sredA[rl][colg] = s; sredB[rl][colg] = s2; }
    }
    __syncthreads();
#pragma unroll
    for (int rt = 0; rt < 2; rt++)
#pragma unroll
    for (int i = 0; i < 4; i++) {
        const int rl = rowbase + 16 * rt + quad * 4 + i;
        const float s = sredA[rl][0] + sredA[rl][1] + sredA[rl][2] + sredA[rl][3];
        const float s2 = sredB[rl][0] + sredB[rl][1] + sredB[rl][2] + sredB[rl][3];
        const float mu = s * (1.f / D_);
        const float rs = rsqrtf(s2 * (1.f / D_) - mu * mu + 1e-5f);
#pragma unroll
        for (int ct = 0; ct < 4; ct++) {
            const float c = acc2[rt][ct][i] + bv[ct];
            out[(size_t)(row0 + rl) * D_ + colv[ct]] = split_pack((c - mu) * rs * gv[ct] + bbv[ct]);
        }
    }
}

// ---------- lite MFMA global k-max, full-width blocks (grid 4096) ----------
__global__ void __launch_bounds__(256) k_dmax(
    const unsigned* __restrict__ kg, const unsigned* __restrict__ P2, int* __restrict__ slot)
{
    __shared__ __align__(16) ushort A2s[64 * 40];
    __shared__ __align__(16) ushort Ps[256 * 40];
    __shared__ float sred[4];
    const int t = threadIdx.x;
    const size_t row0 = (size_t)blockIdx.x * 64;
    {
        const int row = t >> 2, seg = t & 3;
        const unsigned* src = kg + (row0 + row) * DH_ + seg * 8;
        const uint4 f0 = *(const uint4*)src;
        const uint4 f1 = *(const uint4*)(src + 4);
        *(uint4*)&A2s[row * 40 + seg * 8] =
            make_uint4(hpair(f0.x, f0.y), hpair(f0.z, f0.w), hpair(f1.x, f1.y), hpair(f1.z, f1.w));
    }
    {
        const int col = t;
        const unsigned* src = P2 + (size_t)col * DH_;
#pragma unroll
        for (int hf = 0; hf < 2; hf++) {
            const uint4 g0 = *(const uint4*)(src + hf * 16);
            const uint4 g1 = *(const uint4*)(src + hf * 16 + 4);
            const uint4 g2 = *(const uint4*)(src + hf * 16 + 8);
            const uint4 g3 = *(const uint4*)(src + hf * 16 + 12);
            *(uint4*)&Ps[col * 40 + hf * 16] =
                make_uint4(hpair(g0.x, g0.y), hpair(g0.z, g0.w), hpair(g1.x, g1.y), hpair(g1.z, g1.w));
            *(uint4*)&Ps[col * 40 + hf * 16 + 8] =
                make_uint4(hpair(g2.x, g2.y), hpair(g2.z, g2.w), hpair(g3.x, g3.y), hpair(g3.z, g3.w));
        }
    }
    __syncthreads();
    const int w = t >> 6, lane = t & 63, quad = lane >> 4, l16 = lane & 15;
    floatx4 acc[4][4];
#pragma unroll
    for (int rt = 0; rt < 4; rt++)
#pragma unroll
        for (int ct = 0; ct < 4; ct++) acc[rt][ct] = (floatx4){0.f, 0.f, 0.f, 0.f};
    short8 af[4], bf[4];
#pragma unroll
    for (int rt = 0; rt < 4; rt++)
        af[rt] = *(const short8*)&A2s[(rt * 16 + l16) * 40 + quad * 8];
#pragma unroll
    for (int ct = 0; ct < 4; ct++)
        bf[ct] = *(const short8*)&Ps[((w * 4 + ct) * 16 + l16) * 40 + quad * 8];
#pragma unroll
    for (int rt = 0; rt < 4; rt++)
#pragma unroll
        for (int ct = 0; ct < 4; ct++)
            acc[rt][ct] = __builtin_amdgcn_mfma_f32_16x16x32_bf16(af[rt], bf[ct], acc[rt][ct], 0, 0, 0);
    float mx = -INFINITY;
#pragma unroll
    for (int rt = 0; rt < 4; rt++)
#pragma unroll
        for (int ct = 0; ct < 4; ct++)
#pragma unroll
            for (int i = 0; i < 4; i++) mx = fmaxf(mx, acc[rt][ct][i]);
#pragma unroll
    for (int o = 32; o > 0; o >>= 1) mx = fmaxf(mx, __shfl_xor(mx, o, 64));
    if (lane == 0) sred[w] = mx;
    __syncthreads();
    if (t == 0) {
        const float m4 = fmaxf(fmaxf(sred[0], sred[1]), fmaxf(sred[2], sred[3]))
                       * 0.42044820762685725f;
        const int i = __float_as_int(m4);
        atomicMax(slot, (i >= 0) ? i : (i ^ 0x7fffffff));
    }
}

// ---------- performer attention v5d ----------
__global__ void __launch_bounds__(1024) k_attn2(
    const unsigned* __restrict__ qg, const unsigned* __restrict__ kg, const unsigned* __restrict__ vg,
    const unsigned* __restrict__ P2, const int* __restrict__ slot,
    unsigned* __restrict__ outp)
{
    extern __shared__ char smem[];
    ushort* sAh   = (ushort*)(smem);            // [128][40] K h-plane
    ushort* sAl   = (ushort*)(smem + 10240);    // [128][40] K l-plane
    ushort* sBh   = (ushort*)(smem + 20480);    // [64][40] P-quarter h
    ushort* sBl   = (ushort*)(smem + 25600);    // [64][40] P-quarter l
    ushort* kpS   = (ushort*)(smem + 30720);    // [64][136] kp bf16 compact; oRed alias
    ushort* sV    = (ushort*)(smem + 48128);    // [32][136] v bf16 compact
    ushort* sCtx  = (ushort*)(smem + 56832);    // [32][264] ctx bf16 compact
    float* sdk    = (float*)(smem + 73728);     // [128] (+kmax fold)
    float* sdq    = (float*)(smem + 74240);     // [128]
    float* smaxP  = (float*)(smem + 74752);     // [2][128]
    float* sdenP  = smaxP;                      // ALIAS (smaxP dead after dmq)
    float* sksum  = (float*)(smem + 75776);     // [256]
    float* sksP   = (float*)(smem + 76800);     // [16][32]

    const int bh = blockIdx.x;
    const int b = bh >> 3, hh = bh & 7;
    const int t = threadIdx.x;
    const int w = t >> 6, lane = t & 63, quad = lane >> 4, l16 = lane & 15;
    const int wg = w & 7, wh = w >> 3;
    const int nq = wg * 16 + l16;
    const unsigned* kb = kg + (size_t)bh * S_ * DH_;
    const unsigned* qb = qg + (size_t)bh * S_ * DH_;
    const unsigned* vb = vg + (size_t)bh * S_ * DH_;
    const float nrm = 0.42044820762685725f;
    const float diagc = 0.5f * nrm * nrm;
    const float ratio = 0.0625f;

    union U8 { uint4 u; short8 s; };
    union U4 { uint2 u; bfx4 s; };

    float kmaxv;
    { const int iv = *slot; kmaxv = __int_as_float((iv >= 0) ? iv : (iv ^ 0x7fffffff)); }

    short8 qfh, qfl;
    {
        const unsigned* qrow = qb + (size_t)nq * DH_ + quad * 8;
        const uint4 q0 = *(const uint4*)qrow;
        const uint4 q1 = *(const uint4*)(qrow + 4);
        U8 th; th.u = make_uint4(hpair(q0.x, q0.y), hpair(q0.z, q0.w), hpair(q1.x, q1.y), hpair(q1.z, q1.w));
        U8 tl; tl.u = make_uint4(lpair(q0.x, q0.y), lpair(q0.z, q0.w), lpair(q1.x, q1.y), lpair(q1.z, q1.w));
        qfh = th.s; qfl = tl.s;
    }

    if (t < 512) {
        const int row = t >> 2, seg = t & 3;
        const unsigned* src = kb + row * DH_ + seg * 8;
        const uint4 f0 = *(const uint4*)&src[0];
        const uint4 f1 = *(const uint4*)&src[4];
        *(uint4*)&sAh[row * 40 + seg * 8] =
            make_uint4(hpair(f0.x, f0.y), hpair(f0.z, f0.w), hpair(f1.x, f1.y), hpair(f1.z, f1.w));
        *(uint4*)&sAl[row * 40 + seg * 8] =
            make_uint4(lpair(f0.x, f0.y), lpair(f0.z, f0.w), lpair(f1.x, f1.y), lpair(f1.z, f1.w));
    } else {
        const int tt2 = t - 512;
        const int n = tt2 & 127, d0 = (tt2 >> 7) * 8;
        const unsigned* src = vb + n * DH_ + d0;
        const uint4 f0 = *(const uint4*)&src[0];
        const uint4 f1 = *(const uint4*)&src[4];
        const unsigned uu[8] = {f0.x, f0.y, f0.z, f0.w, f1.x, f1.y, f1.z, f1.w};
#pragma unroll
        for (int j = 0; j < 8; j++)
            sV[(d0 + j) * 136 + n] = (ushort)(uu[j] & 0xffffu);
    }
    if (t < 128) {
        float s = 0.f, s2 = 0.f;
#pragma unroll
        for (int d4 = 0; d4 < DH_ / 4; d4++) {
            const uint4 kk = *(const uint4*)&kb[t * DH_ + d4 * 4];
            const float k0 = rec(kk.x), k1 = rec(kk.y), k2 = rec(kk.z), k3 = rec(kk.w);
            s += k0 * k0 + k1 * k1 + k2 * k2 + k3 * k3;
            const uint4 qq = *(const uint4*)&qb[t * DH_ + d4 * 4];
            const float q0 = rec(qq.x), q1 = rec(qq.y), q2 = rec(qq.z), q3 = rec(qq.w);
            s2 += q0 * q0 + q1 * q1 + q2 * q2 + q3 * q3;
        }
        sdk[t] = s * diagc + kmaxv;
        sdq[t] = s2 * diagc;
    }
    __syncthreads();

    floatx4 adq[2][4];
#pragma unroll
    for (int j = 0; j < 2; j++)
#pragma unroll
        for (int mtl = 0; mtl < 4; mtl++) adq[j][mtl] = (floatx4){0.f, 0.f, 0.f, 0.f};

#pragma unroll
    for (int qd = 0; qd < 4; qd++) {
        {
            const int col = t >> 4, ch2 = t & 15;
            const unsigned* src = P2 + (size_t)(qd * 64 + col) * DH_ + ch2 * 2;
            const unsigned u0 = src[0], u1 = src[1];
            ((unsigned*)sBh)[col * 20 + ch2] = hpair(u0, u1);
            ((unsigned*)sBl)[col * 20 + ch2] = lpair(u0, u1);
        }
        __syncthreads();
        floatx4 acc[2];
        acc[0] = (floatx4){0.f, 0.f, 0.f, 0.f};
        acc[1] = (floatx4){0.f, 0.f, 0.f, 0.f};
        {
            const short8 afh = *(const short8*)&sAh[nq * 40 + quad * 8];
            const short8 afl = *(const short8*)&sAl[nq * 40 + quad * 8];
#pragma unroll
            for (int ctl = 0; ctl < 2; ctl++) {
                const int mrow = ((2 * wh + ctl) * 16 + l16) * 40 + quad * 8;
                const short8 bfh = *(const short8*)&sBh[mrow];
                const short8 bfl = *(const short8*)&sBl[mrow];
                acc[ctl] = __builtin_amdgcn_mfma_f32_16x16x32_bf16(afh, bfh, acc[ctl], 0, 0, 0);
                acc[ctl] = __builtin_amdgcn_mfma_f32_16x16x32_bf16(afh, bfl, acc[ctl], 0, 0, 0);
                acc[ctl] = __builtin_amdgcn_mfma_f32_16x16x32_bf16(afl, bfh, acc[ctl], 0, 0, 0);
            }
        }
        float kc[2];
#pragma unroll
        for (int ctl = 0; ctl < 2; ctl++) {
            float kcl = 0.f;
            ushort kh[4];
#pragma unroll
            for (int i = 0; i < 4; i++) {
                const int n = wg * 16 + quad * 4 + i;
                const float kp = ratio * (__expf(acc[ctl][i] * nrm - sdk[n]) + 1e-4f);
                kh[i] = bf16_rn(kp);
                kcl += __uint_as_float((unsigned)kh[i] << 16);
            }
            *(uint2*)&kpS[((2 * wh + ctl) * 16 + l16) * 136 + wg * 16 + quad * 4] =
                make_uint2((unsigned)kh[0] | ((unsigned)kh[1] << 16),
                           (unsigned)kh[2] | ((unsigned)kh[3] << 16));
            kc[ctl] = kcl;
        }
#pragma unroll
        for (int ctl = 0; ctl < 2; ctl++) {
            kc[ctl] += __shfl_xor(kc[ctl], 16, 64);
            kc[ctl] += __shfl_xor(kc[ctl], 32, 64);
        }
        if (quad == 0) {
            sksP[w * 32 + l16] = kc[0];
            sksP[w * 32 + 16 + l16] = kc[1];
        }
        __syncthreads();
        const int qown = (qd & 1) ^ 1;
        if (wh == qown) {
            const int aidx2 = qd >> 1;
#pragma unroll
            for (int mtl = 0; mtl < 4; mtl++) {
                const int prow = (mtl * 16 + l16) * 40 + quad * 8;
                const short8 aPh = *(const short8*)&sBh[prow];
                const short8 aPl = *(const short8*)&sBl[prow];
                adq[aidx2][mtl] = __builtin_amdgcn_mfma_f32_16x16x32_bf16(aPh, qfh, adq[aidx2][mtl], 0, 0, 0);
                adq[aidx2][mtl] = __builtin_amdgcn_mfma_f32_16x16x32_bf16(aPh, qfl, adq[aidx2][mtl], 0, 0, 0);
                adq[aidx2][mtl] = __builtin_amdgcn_mfma_f32_16x16x32_bf16(aPl, qfh, adq[aidx2][mtl], 0, 0, 0);
            }
        } else {
            const int mt = wg & 3, dt = wg >> 2;
            floatx4 cacc = (floatx4){0.f, 0.f, 0.f, 0.f};
#pragma unroll
            for (int ks = 0; ks < 4; ks++) {
                const short8 a = *(const short8*)&kpS[(mt * 16 + l16) * 136 + ks * 32 + quad * 8];
                const short8 bvv = *(const short8*)&sV[(dt * 16 + l16) * 136 + ks * 32 + quad * 8];
                cacc = __builtin_amdgcn_mfma_f32_16x16x32_bf16(a, bvv, cacc, 0, 0, 0);
            }
            ushort ch[4];
#pragma unroll
            for (int i = 0; i < 4; i++) ch[i] = bf16_rn(cacc[i]);
            *(uint2*)&sCtx[(dt * 16 + l16) * 264 + qd * 64 + mt * 16 + quad * 4] =
                make_uint2((unsigned)ch[0] | ((unsigned)ch[1] << 16),
                           (unsigned)ch[2] | ((unsigned)ch[3] << 16));
        }
        if (t < 64) {
            float s = 0.f;
#pragma unroll
            for (int wg2 = 0; wg2 < 8; wg2++)
                s += sksP[((t >> 5) * 8 + wg2) * 32 + (t & 31)];
            sksum[qd * 64 + t] = s;
        }
        __syncthreads();
    }

    {
        float mxn = -INFINITY;
#pragma unroll
        for (int j = 0; j < 2; j++)
#pragma unroll
            for (int mtl = 0; mtl < 4; mtl++)
#pragma unroll
                for (int i = 0; i < 4; i++) mxn = fmaxf(mxn, adq[j][mtl][i]);
        mxn = fmaxf(mxn, __shfl_xor(mxn, 16, 64));
        mxn = fmaxf(mxn, __shfl_xor(mxn, 32, 64));
        if (quad == 0) smaxP[wh * 128 + nq] = mxn;
    }
    __syncthreads();
    const float dmq = sdq[nq] + fmaxf(smaxP[nq], smaxP[128 + nq]) * nrm;

    floatx4 oT[2];
    oT[0] = (floatx4){0.f, 0.f, 0.f, 0.f};
    oT[1] = (floatx4){0.f, 0.f, 0.f, 0.f};
    float dp = 0.f;
#pragma unroll
    for (int j = 0; j < 2; j++) {
        const int qdo = 2 * j + (wh ^ 1);
#pragma unroll
        for (int mtl = 0; mtl < 4; mtl++) {
            ushort qh[4];
#pragma unroll
            for (int i = 0; i < 4; i++) {
                const float qp = ratio * (__expf(adq[j][mtl][i] * nrm - dmq) + 1e-4f);
                qh[i] = bf16_rn(qp);
                dp += __uint_as_float((unsigned)qh[i] << 16)
                    * sksum[qdo * 64 + mtl * 16 + quad * 4 + i];
            }
            U4 tb;
            tb.u = make_uint2((unsigned)qh[0] | ((unsigned)qh[1] << 16),
                              (unsigned)qh[2] | ((unsigned)qh[3] << 16));
#pragma unroll
            for (int dt = 0; dt < 2; dt++) {
                U4 ta;
                ta.u = *(const uint2*)&sCtx[(dt * 16 + l16) * 264 + qdo * 64 + mtl * 16 + quad * 4];
                oT[dt] = __builtin_amdgcn_mfma_f32_16x16x16bf16_1k(ta.s, tb.s, oT[dt], 0, 0, 0);
            }
        }
    }
    dp += __shfl_xor(dp, 16, 64);
    dp += __shfl_xor(dp, 32, 64);
    __syncthreads();   // all smaxP reads (dmq) done before sdenP overlay writes
    if (quad == 0) sdenP[wh * 128 + nq] = dp;

    float* oRed = (float*)kpS;
    if (wh == 1) {
#pragma unroll
        for (int dt = 0; dt < 2; dt++)
            *(floatx4*)&oRed[((wg * 2 + dt) * 64 + lane) * 4] = oT[dt];
    }
    __syncthreads();
    if (wh == 0) {
        const float inv = 1.0f / (sdenP[nq] + sdenP[128 + nq]);
#pragma unroll
        for (int dt = 0; dt < 2; dt++) {
            const floatx4 o2 = *(const floatx4*)&oRed[((wg * 2 + dt) * 64 + lane) * 4];
            const unsigned r0 = split_pack((oT[dt][0] + o2[0]) * inv);
            const unsigned r1 = split_pack((oT[dt][1] + o2[1]) * inv);
            const unsigned r2 = split_pack((oT[dt][2] + o2[2]) * inv);
            const unsigned r3 = split_pack((oT[dt][3] + o2[3]) * inv);
            *(uint4*)&outp[((size_t)b * S_ + nq) * D_ + hh * DH_ + dt * 16 + quad * 4] =
                make_uint4(r0, r1, r2, r3);
        }
    }
}

// ---------- classification head (packed input) ----------
__global__ void __launch_bounds__(256) k_head(
    const unsigned* __restrict__ hfin, const float* __restrict__ h1w, const float* __restrict__ h1b,
    const float* __restrict__ h2w, const float* __restrict__ h2b,
    const float* __restrict__ ow, const float* __restrict__ ob, float* __restrict__ outp)
{
    __shared__ float c0[D_];
    __shared__ float c1[2 * HID_];
    __shared__ float sred[4];
    const int t = threadIdx.x;
    const int b = blockIdx.x;
    c0[t] = rec(hfin[(size_t)b * S_ * D_ + t]);
    __syncthreads();
#pragma unroll
    for (int half = 0; half < 2; half++) {
        const int j = half * 256 + t;
        float a = h1b[j];
        const float* w = h1w + (size_t)j * D_;
        for (int d = 0; d < D_; d += 4) {
            const float4 w4 = *(const float4*)&w[d];
            const float4 x4 = *(const float4*)&c0[d];
            a += x4.x * w4.x + x4.y * w4.y + x4.z * w4.z + x4.w * w4.w;
        }
        c1[j] = (a >= 0.f) ? a : 0.2f * a;
    }
    __syncthreads();
    float a2 = h2b[t];
    const float* w2 = h2w + (size_t)t * (2 * HID_);
    for (int j = 0; j < 2 * HID_; j += 4) {
        const float4 w4 = *(const float4*)&w2[j];
        const float4 x4 = *(const float4*)&c1[j];
        a2 += x4.x * w4.x + x4.y * w4.y + x4.z * w4.z + x4.w * w4.w;
    }
    const float c2 = (a2 >= 0.f) ? a2 : 0.2f * a2;
    const float s = blk_sum(c2 * ow[t], sred);
    if (t == 0) outp[b] = s + ob[0];
}

extern "C" void kernel_launch(void* const* d_in, const int* in_sizes, int n_in,
                              void* d_out, int out_size, void* d_ws, size_t ws_size,
                              hipStream_t stream)
{
    const float* x     = (const float*)d_in[0];
    const int*   mask  = (const int*)d_in[1];
    const float* emb_w = (const float*)d_in[2];
    const float* emb_b = (const float*)d_in[3];
    const float* Wq    = (const float*)d_in[4];
    const float* bq    = (const float*)d_in[5];
    const float* Wk    = (const float*)d_in[6];
    const float* bk    = (const float*)d_in[7];
    const float* Wv    = (const float*)d_in[8];
    const float* bv    = (const float*)d_in[9];
    const float* Wo    = (const float*)d_in[10];
    const float* bo    = (const float*)d_in[11];
    const float* proj  = (const float*)d_in[12];
    const float* n1w   = (const float*)d_in[13];
    const float* n1b   = (const float*)d_in[14];
    const float* n2w   = (const float*)d_in[15];
    const float* n2b   = (const float*)d_in[16];
    const float* f1w   = (const float*)d_in[17];
    const float* f1b   = (const float*)d_in[18];
    const float* f2w   = (const float*)d_in[19];
    const float* f2b   = (const float*)d_in[20];
    const float* h1w   = (const float*)d_in[21];
    const float* h1b   = (const float*)d_in[22];
    const float* h2w   = (const float*)d_in[23];
    const float* h2b   = (const float*)d_in[24];
    const float* ow    = (const float*)d_in[25];
    const float* ob    = (const float*)d_in[26];

    const size_t BSD = (size_t)B_ * S_ * D_;
    unsigned* A = (unsigned*)d_ws;                 // packed activations
    unsigned* Q = A + BSD;
    unsigned* K = Q + BSD;
    unsigned* V = K + BSD;
    const size_t WMU = 65536;                      // ushorts per matrix plane (256x256)
    ushort* WH = (ushort*)(V + BSD);               // 6 x L x 65536 ushorts (h planes)
    ushort* WL = WH + 6 * L_ * WMU;                // 6 x L x 65536 ushorts (l planes)
    unsigned* P2 = (unsigned*)(WL + 6 * L_ * WMU); // compact split proj: L x 256 x 32 uints
    int* slots = (int*)(P2 + (size_t)L_ * M_ * DH_);

    // fused prep: weights + proj + reset + embedding (blocks 801..8992)
    k_prep<<<801 + 8192, 256, 0, stream>>>(Wq, Wk, Wv, Wo, f1w, f2w, proj, WH, WL, P2, slots,
                                           x, emb_w, emb_b, A);

    const int GB2 = B_ * S_ / 128;             // 256 blocks per 128-row GEMM
    const int DB = B_ * H_ * S_ / 64;          // 4096 blocks for k_dmax
    const size_t ATTN_LDS = 78848;             // 77 KB dynamic LDS

    for (int l = 0; l < L_; l++) {
        const unsigned* P2l = P2 + (size_t)l * M_ * DH_;
        k_gemm_qkv<<<3 * GB2, 512, 0, stream>>>(A, WH, WL, l, bq + l * D_, bk + l * D_, bv + l * D_, mask, Q, K, V);
        k_dmax<<<DB, 256, 0, stream>>>(K, P2l, slots + l);
        k_attn2<<<B_ * H_, 1024, ATTN_LDS, stream>>>(Q, K, V, P2l, slots + l, A);
        k_wofn<<<B_ * S_ / 64, 512, 0, stream>>>(A,
            WH + (3 * L_ + l) * WMU, WL + (3 * L_ + l) * WMU,
            WH + (4 * L_ + l) * WMU, WL + (4 * L_ + l) * WMU,
            WH + (5 * L_ + l) * WMU, WL + (5 * L_ + l) * WMU,
            bo + l * D_, n1w + l * D_, n1b + l * D_,
            f1b + l * HID_, f2b + l * D_, n2w + l * D_, n2b + l * D_, A);
    }
    k_head<<<B_, 256, 0, stream>>>(A, h1w, h1b, h2w, h2b, ow, ob, (float*)d_out);
}

// Round 20
// 1019.324 us; speedup vs baseline: 1.1508x; 1.1235x over previous
//
#include <hip/hip_runtime.h>
#include <math.h>

#define B_ 256
#define N_ 127
#define S_ 128
#define NDIM_ 3
#define D_ 256
#define H_ 8
#define DH_ 32
#define M_ 256
#define HID_ 256
#define L_ 4
#define LOG2E 1.44269504088896340736f

typedef __attribute__((ext_vector_type(8))) short short8;
typedef __attribute__((ext_vector_type(4))) short bfx4;
typedef __attribute__((ext_vector_type(4))) float floatx4;

// ---------- bf16 split helpers ----------
__device__ __forceinline__ ushort bf16_rn(float x) {
    unsigned u = __float_as_uint(x);
    u = (u + 0x7fffu + ((u >> 16) & 1u)) >> 16;
    return (ushort)u;
}
__device__ __forceinline__ unsigned split_pack(float x) {
    const ushort h = bf16_rn(x);
    const float r = x - __uint_as_float(((unsigned)h) << 16);
    const ushort l = bf16_rn(r);
    return (unsigned)h | ((unsigned)l << 16);
}
__device__ __forceinline__ float rec(unsigned u) {
    return __uint_as_float(u << 16) + __uint_as_float(u & 0xffff0000u);
}
__device__ __forceinline__ unsigned hpair(unsigned u0, unsigned u1) {
    return (u0 & 0xffffu) | (u1 << 16);
}
__device__ __forceinline__ unsigned lpair(unsigned u0, unsigned u1) {
    return (u0 >> 16) | (u1 & 0xffff0000u);
}

// ---------- block reductions ----------
__device__ __forceinline__ float blk_sum(float v, float* sred) {
#pragma unroll
    for (int o = 32; o > 0; o >>= 1) v += __shfl_xor(v, o, 64);
    if ((threadIdx.x & 63) == 0) sred[threadIdx.x >> 6] = v;
    __syncthreads();
    v = sred[0] + sred[1] + sred[2] + sred[3];
    __syncthreads();
    return v;
}

// ---------- fused prep: weight planes + proj conv + slot reset + embedding ----------
__global__ void __launch_bounds__(256) k_prep(
    const float* __restrict__ Wq, const float* __restrict__ Wk, const float* __restrict__ Wv,
    const float* __restrict__ Wo, const float* __restrict__ f1w, const float* __restrict__ f2w,
    const float* __restrict__ proj, ushort* __restrict__ WH, ushort* __restrict__ WL,
    unsigned* __restrict__ P2, int* __restrict__ slots,
    const float* __restrict__ x, const float* __restrict__ ew, const float* __restrict__ eb,
    unsigned* __restrict__ Aout)
{
    const int bid = blockIdx.x;
    if (bid < 768) {
        const int tensor = bid / 128;
        const int tid = (bid & 127) * 256 + threadIdx.x;
        const float* src = tensor == 0 ? Wq : tensor == 1 ? Wk : tensor == 2 ? Wv
                         : tensor == 3 ? Wo : tensor == 4 ? f1w : f2w;
        ushort* dh = WH + (size_t)tensor * L_ * 65536;
        ushort* dl = WL + (size_t)tensor * L_ * 65536;
        const int l = tid >> 13;
        const int col = (tid >> 5) & 255, kc = tid & 31;
        const float* sp = src + ((size_t)l << 16) + col * 256 + kc * 8;
        float v[8];
        *(float4*)&v[0] = *(const float4*)sp;
        *(float4*)&v[4] = *(const float4*)(sp + 4);
        unsigned hu[4], lu[4];
#pragma unroll
        for (int i = 0; i < 4; i++) {
            const unsigned u0 = split_pack(v[2 * i]);
            const unsigned u1 = split_pack(v[2 * i + 1]);
            hu[i] = hpair(u0, u1);
            lu[i] = lpair(u0, u1);
        }
        const size_t off = ((size_t)l << 16) + ((size_t)(kc * 256 + col)) * 8;
        *(uint4*)&dh[off] = make_uint4(hu[0], hu[1], hu[2], hu[3]);
        *(uint4*)&dl[off] = make_uint4(lu[0], lu[1], lu[2], lu[3]);
    } else if (bid < 800) {
        const int idx = ((bid - 768) * 256 + threadIdx.x) * 4;
        const float4 w4 = *(const float4*)&proj[idx];
        const float v[4] = {w4.x, w4.y, w4.z, w4.w};
        unsigned u[4];
#pragma unroll
        for (int i = 0; i < 4; i++) u[i] = split_pack(v[i]);
        *(uint4*)&P2[idx] = make_uint4(u[0], u[1], u[2], u[3]);
    } else if (bid == 800) {
        if (threadIdx.x < 4) {
            const int i = __float_as_int(-INFINITY);
            slots[threadIdx.x] = (i >= 0) ? i : (i ^ 0x7fffffff);
        }
    } else {
        const int idx4 = (bid - 801) * 256 + threadIdx.x;
        const int d0 = (idx4 & 63) * 4;
        const int n = (idx4 >> 6) & (S_ - 1);
        const int b = idx4 >> 13;
        unsigned r[4] = {0u, 0u, 0u, 0u};
        if (n > 0) {
            const float* xr = x + ((size_t)b * N_ + (n - 1)) * NDIM_;
            const float x0 = xr[0], x1 = xr[1], x2 = xr[2];
#pragma unroll
            for (int j = 0; j < 4; j++) {
                const int d = d0 + j;
                const float val = eb[d] + x0 * ew[d * 3 + 0] + x1 * ew[d * 3 + 1] + x2 * ew[d * 3 + 2];
                r[j] = split_pack(val);
            }
        }
        *(uint4*)&Aout[(size_t)idx4 * 4] = make_uint4(r[0], r[1], r[2], r[3]);
    }
}

// ---------- fused Q/K/V GEMM, 128-row tiles (grid 768) — R17 proven-best ----------
__global__ void __launch_bounds__(512, 2) k_gemm_qkv(
    const unsigned* __restrict__ Ap, const ushort* __restrict__ WHb,
    const ushort* __restrict__ WLb, const int l,
    const float* __restrict__ bq, const float* __restrict__ bk, const float* __restrict__ bv_,
    const int* __restrict__ mask,
    unsigned* __restrict__ Qo, unsigned* __restrict__ Ko, unsigned* __restrict__ Vo)
{
    __shared__ ushort sAh[2][4160];
    __shared__ ushort sAl[2][4160];
    const int t = threadIdx.x;
    const int w = t >> 6, lane = t & 63;
    const int quad = lane >> 4, l16 = lane & 15;
    const int rowbase = 64 * (w >> 2), colbase = 64 * (w & 3);
    const int which = blockIdx.x >> 8;
    const int row0 = (blockIdx.x & 255) * 128;
    const ushort* WH = WHb + ((size_t)(which * L_ + l)) * 65536;
    const ushort* WL = WLb + ((size_t)(which * L_ + l)) * 65536;
    const float* bias = which == 0 ? bq : which == 1 ? bk : bv_;
    unsigned* out = which == 0 ? Qo : which == 1 ? Ko : Vo;

    floatx4 acc[4][4];
#pragma unroll
    for (int rt = 0; rt < 4; rt++)
#pragma unroll
        for (int ct = 0; ct < 4; ct++) acc[rt][ct] = (floatx4){0.f, 0.f, 0.f, 0.f};

    const int arow = t >> 2, achunk = t & 3;
    const unsigned* AG = Ap + (size_t)(row0 + arow) * D_ + achunk * 8;
    const int aidx = achunk * 1040 + arow * 8;

    {
        const uint4 a0 = *(const uint4*)AG;
        const uint4 a1 = *(const uint4*)(AG + 4);
        *(uint4*)&sAh[0][aidx] = make_uint4(hpair(a0.x, a0.y), hpair(a0.z, a0.w),
                                            hpair(a1.x, a1.y), hpair(a1.z, a1.w));
        *(uint4*)&sAl[0][aidx] = make_uint4(lpair(a0.x, a0.y), lpair(a0.z, a0.w),
                                            lpair(a1.x, a1.y), lpair(a1.z, a1.w));
    }
    __syncthreads();

    for (int s = 0; s < 8; s++) {
        const int p = s & 1;
        uint4 a0n, a1n;
        if (s + 1 < 8) {
            a0n = *(const uint4*)(AG + (s + 1) * 32);
            a1n = *(const uint4*)(AG + (s + 1) * 32 + 4);
        }
        const size_t wbase = ((size_t)((s * 4 + quad) * 256 + colbase + l16)) * 8;
        const ushort* WHf = WH + wbase;
        const ushort* WLf = WL + wbase;
        short8 ah[4], al[4], wh[4], wl[4];
#pragma unroll
        for (int ct = 0; ct < 4; ct++) {
            wh[ct] = *(const short8*)&WHf[ct * 128];
            wl[ct] = *(const short8*)&WLf[ct * 128];
        }
#pragma unroll
        for (int rt = 0; rt < 4; rt++) {
            const int ai = quad * 1040 + (rowbase + 16 * rt + l16) * 8;
            ah[rt] = *(const short8*)&sAh[p][ai];
            al[rt] = *(const short8*)&sAl[p][ai];
        }
#pragma unroll
        for (int rt = 0; rt < 4; rt++)
#pragma unroll
            for (int ct = 0; ct < 4; ct++) {
                acc[rt][ct] = __builtin_amdgcn_mfma_f32_16x16x32_bf16(ah[rt], wh[ct], acc[rt][ct], 0, 0, 0);
                acc[rt][ct] = __builtin_amdgcn_mfma_f32_16x16x32_bf16(ah[rt], wl[ct], acc[rt][ct], 0, 0, 0);
                acc[rt][ct] = __builtin_amdgcn_mfma_f32_16x16x32_bf16(al[rt], wh[ct], acc[rt][ct], 0, 0, 0);
            }
        if (s + 1 < 8) {
            *(uint4*)&sAh[p ^ 1][aidx] = make_uint4(hpair(a0n.x, a0n.y), hpair(a0n.z, a0n.w),
                                                    hpair(a1n.x, a1n.y), hpair(a1n.z, a1n.w));
            *(uint4*)&sAl[p ^ 1][aidx] = make_uint4(lpair(a0n.x, a0n.y), lpair(a0n.z, a0n.w),
                                                    lpair(a1n.x, a1n.y), lpair(a1n.z, a1n.w));
        }
        __syncthreads();
    }

    int colv[4]; float bv[4];
#pragma unroll
    for (int ct = 0; ct < 4; ct++) { colv[ct] = colbase + 16 * ct + l16; bv[ct] = bias[colv[ct]]; }

    const int b = row0 >> 7;
#pragma unroll
    for (int rt = 0; rt < 4; rt++)
#pragma unroll
    for (int i = 0; i < 4; i++) {
        const int rl = rowbase + 16 * rt + quad * 4 + i;
        const int n = (row0 + rl) & (S_ - 1);
        float keep = 1.f;
        if (which == 2) keep = (n == 0) ? 1.f : (mask[b * N_ + n - 1] ? 0.f : 1.f);
#pragma unroll
        for (int ct = 0; ct < 4; ct++) {
            float c = acc[rt][ct][i] + bv[ct];
            c *= keep;
            const int col = colv[ct];
            out[(((size_t)b * H_ + (col >> 5)) * S_ + n) * DH_ + (col & 31)] = split_pack(c);
        }
    }
}

// ---------- fused Wo+LN1+FFN+LN2 mega-kernel (64-row blocks, grid 512) ----------
__global__ void __launch_bounds__(512, 2) k_wofn(
    const unsigned* __restrict__ Ap,
    const ushort* __restrict__ WoH, const ushort* __restrict__ WoL,
    const ushort* __restrict__ W1H, const ushort* __restrict__ W1L,
    const ushort* __restrict__ W2H, const ushort* __restrict__ W2L,
    const float* __restrict__ bo, const float* __restrict__ n1w, const float* __restrict__ n1b,
    const float* __restrict__ b1, const float* __restrict__ b2,
    const float* __restrict__ g2w, const float* __restrict__ g2b,
    unsigned* __restrict__ out)
{
    __shared__ char smemc[67584];
    ushort* Th  = (ushort*)smemc;              // [64][264] T planes; later G1
    ushort* Tl  = (ushort*)(smemc + 33792);
    ushort* sTh = (ushort*)smemc;              // [2][2080] A staging (alias, dead first)
    ushort* sTl = (ushort*)(smemc + 8320);
    __shared__ float sredA[64][8], sredB[64][8];
    const int t = threadIdx.x;
    const int w = t >> 6, lane = t & 63;
    const int quad = lane >> 4, l16 = lane & 15;
    const int row0 = blockIdx.x * 64;

    // ---- stage 0: T^T = Wo^T x A^T ----
    floatx4 acc[2][4];
#pragma unroll
    for (int rt = 0; rt < 2; rt++)
#pragma unroll
        for (int ct = 0; ct < 4; ct++) acc[rt][ct] = (floatx4){0.f, 0.f, 0.f, 0.f};

    const int arow = t >> 3, akq = t & 7;
    const unsigned* AG = Ap + (size_t)(row0 + arow) * D_ + akq * 4;
    const int aidx = (akq >> 1) * 520 + arow * 8 + (akq & 1) * 4;

    {
        const uint4 a4 = *(const uint4*)AG;
        *(uint2*)&sTh[aidx] = make_uint2(hpair(a4.x, a4.y), hpair(a4.z, a4.w));
        *(uint2*)&sTl[aidx] = make_uint2(lpair(a4.x, a4.y), lpair(a4.z, a4.w));
    }
    __syncthreads();

    for (int s = 0; s < 8; s++) {
        const int p = s & 1;
        uint4 a_n;
        if (s + 1 < 8) a_n = *(const uint4*)(AG + (s + 1) * 32);
        const size_t wbase = ((size_t)((s * 4 + quad) * 256 + 32 * w + l16)) * 8;
        short8 fh[2], fl[2], th[4], tl[4];
#pragma unroll
        for (int rt = 0; rt < 2; rt++) {
            fh[rt] = *(const short8*)&WoH[wbase + rt * 128];
            fl[rt] = *(const short8*)&WoL[wbase + rt * 128];
        }
#pragma unroll
        for (int ct = 0; ct < 4; ct++) {
            const int ti = p * 2080 + quad * 520 + (16 * ct + l16) * 8;
            th[ct] = *(const short8*)&sTh[ti];
            tl[ct] = *(const short8*)&sTl[ti];
        }
#pragma unroll
        for (int rt = 0; rt < 2; rt++)
#pragma unroll
            for (int ct = 0; ct < 4; ct++) {
                acc[rt][ct] = __builtin_amdgcn_mfma_f32_16x16x32_bf16(fh[rt], th[ct], acc[rt][ct], 0, 0, 0);
                acc[rt][ct] = __builtin_amdgcn_mfma_f32_16x16x32_bf16(fl[rt], th[ct], acc[rt][ct], 0, 0, 0);
                acc[rt][ct] = __builtin_amdgcn_mfma_f32_16x16x32_bf16(fh[rt], tl[ct], acc[rt][ct], 0, 0, 0);
            }
        if (s + 1 < 8) {
            *(uint2*)&sTh[(p ^ 1) * 2080 + aidx] = make_uint2(hpair(a_n.x, a_n.y), hpair(a_n.z, a_n.w));
            *(uint2*)&sTl[(p ^ 1) * 2080 + aidx] = make_uint2(lpair(a_n.x, a_n.y), lpair(a_n.z, a_n.w));
        }
        __syncthreads();
    }

    // ---- LN1 epilogue on T^T layout ----
    {
        float bov[2][4];
#pragma unroll
        for (int rt = 0; rt < 2; rt++)
#pragma unroll
            for (int i = 0; i < 4; i++) bov[rt][i] = bo[32 * w + 16 * rt + quad * 4 + i];
        float ps[4], ps2[4];
#pragma unroll
        for (int ct = 0; ct < 4; ct++) { ps[ct] = 0.f; ps2[ct] = 0.f; }
#pragma unroll
        for (int rt = 0; rt < 2; rt++)
#pragma unroll
        for (int ct = 0; ct < 4; ct++)
#pragma unroll
        for (int i = 0; i < 4; i++) {
            const float c = acc[rt][ct][i] + bov[rt][i];
            acc[rt][ct][i] = c;
            ps[ct] += c; ps2[ct] += c * c;
        }
#pragma unroll
        for (int ct = 0; ct < 4; ct++) {
            ps[ct] += __shfl_xor(ps[ct], 16, 64);  ps[ct] += __shfl_xor(ps[ct], 32, 64);
            ps2[ct] += __shfl_xor(ps2[ct], 16, 64); ps2[ct] += __shfl_xor(ps2[ct], 32, 64);
        }
        if (quad == 0) {
#pragma unroll
            for (int ct = 0; ct < 4; ct++) {
                sredA[16 * ct + l16][w] = ps[ct];
                sredB[16 * ct + l16][w] = ps2[ct];
            }
        }
        __syncthreads();
        float mu[4], rs[4];
#pragma unroll
        for (int ct = 0; ct < 4; ct++) {
            const int n = 16 * ct + l16;
            float s = 0.f, s2 = 0.f;
#pragma unroll
            for (int k = 0; k < 8; k++) { s += sredA[n][k]; s2 += sredB[n][k]; }
            mu[ct] = s * (1.f / D_);
            rs[ct] = rsqrtf(s2 * (1.f / D_) - mu[ct] * mu[ct] + 1e-5f);
        }
        float gv1[2][4], bv1[2][4];
#pragma unroll
        for (int rt = 0; rt < 2; rt++)
#pragma unroll
            for (int i = 0; i < 4; i++) {
                const int c2 = 32 * w + 16 * rt + quad * 4 + i;
                gv1[rt][i] = n1w[c2];
                bv1[rt][i] = n1b[c2];
            }
#pragma unroll
        for (int ct = 0; ct < 4; ct++) {
            const int n = 16 * ct + l16;
#pragma unroll
            for (int rt = 0; rt < 2; rt++) {
                unsigned u[4];
#pragma unroll
                for (int i = 0; i < 4; i++) {
                    const float tv = (acc[rt][ct][i] - mu[ct]) * rs[ct] * gv1[rt][i] + bv1[rt][i];
                    u[i] = split_pack(tv);
                }
                const int base = n * 264 + 32 * w + 16 * rt + quad * 4;
                *(uint2*)&Th[base] = make_uint2(hpair(u[0], u[1]), hpair(u[2], u[3]));
                *(uint2*)&Tl[base] = make_uint2(lpair(u[0], u[1]), lpair(u[2], u[3]));
            }
        }
        __syncthreads();
    }

    // ---- stage 1: G1^T = f1w^T x T (barrier-free K-loop over resident T) ----
    floatx4 acc1[2][4];
#pragma unroll
    for (int rt = 0; rt < 2; rt++)
#pragma unroll
        for (int ct = 0; ct < 4; ct++) acc1[rt][ct] = (floatx4){0.f, 0.f, 0.f, 0.f};

    for (int s = 0; s < 8; s++) {
        const size_t wbase = ((size_t)((s * 4 + quad) * 256 + 32 * w + l16)) * 8;
        short8 fh[2], fl[2], th[4], tl[4];
#pragma unroll
        for (int rt = 0; rt < 2; rt++) {
            fh[rt] = *(const short8*)&W1H[wbase + rt * 128];
            fl[rt] = *(const short8*)&W1L[wbase + rt * 128];
        }
#pragma unroll
        for (int ct = 0; ct < 4; ct++) {
            const int ti = (16 * ct + l16) * 264 + s * 32 + quad * 8;
            th[ct] = *(const short8*)&Th[ti];
            tl[ct] = *(const short8*)&Tl[ti];
        }
#pragma unroll
        for (int rt = 0; rt < 2; rt++)
#pragma unroll
            for (int ct = 0; ct < 4; ct++) {
                acc1[rt][ct] = __builtin_amdgcn_mfma_f32_16x16x32_bf16(fh[rt], th[ct], acc1[rt][ct], 0, 0, 0);
                acc1[rt][ct] = __builtin_amdgcn_mfma_f32_16x16x32_bf16(fl[rt], th[ct], acc1[rt][ct], 0, 0, 0);
                acc1[rt][ct] = __builtin_amdgcn_mfma_f32_16x16x32_bf16(fh[rt], tl[ct], acc1[rt][ct], 0, 0, 0);
            }
    }
    __syncthreads();   // all T reads done before G1 overwrites the planes

    {
        float b1v[2][4];
#pragma unroll
        for (int rt = 0; rt < 2; rt++)
#pragma unroll
            for (int i = 0; i < 4; i++) b1v[rt][i] = b1[32 * w + 16 * rt + quad * 4 + i];
#pragma unroll
        for (int ct = 0; ct < 4; ct++) {
            const int n = 16 * ct + l16;
#pragma unroll
            for (int rt = 0; rt < 2; rt++) {
                unsigned u[4];
#pragma unroll
                for (int i = 0; i < 4; i++) {
                    float c = acc1[rt][ct][i] + b1v[rt][i];
                    c = (c >= 0.f) ? c : 0.2f * c;
                    u[i] = split_pack(c);
                }
                const int base = n * 264 + 32 * w + 16 * rt + quad * 4;
                *(uint2*)&Th[base] = make_uint2(hpair(u[0], u[1]), hpair(u[2], u[3]));
                *(uint2*)&Tl[base] = make_uint2(lpair(u[0], u[1]), lpair(u[2], u[3]));
            }
        }
        __syncthreads();
    }

    // ---- stage 2: out = G1 * f2w + LN2 ----
    const int rowbase = 32 * (w >> 2), colbase = 64 * (w & 3);
    const int colg = w & 3;
    floatx4 acc2[2][4];
#pragma unroll
    for (int rt = 0; rt < 2; rt++)
#pragma unroll
        for (int ct = 0; ct < 4; ct++) acc2[rt][ct] = (floatx4){0.f, 0.f, 0.f, 0.f};

    for (int ks = 0; ks < 8; ks++) {
        const size_t w2base = ((size_t)((ks * 4 + quad) * 256 + colbase + l16)) * 8;
        short8 ah[2], al[2], wh[4], wl[4];
#pragma unroll
        for (int ct = 0; ct < 4; ct++) {
            wh[ct] = *(const short8*)&W2H[w2base + ct * 128];
            wl[ct] = *(const short8*)&W2L[w2base + ct * 128];
        }
#pragma unroll
        for (int rt = 0; rt < 2; rt++) {
            const int gi = (rowbase + 16 * rt + l16) * 264 + ks * 32 + quad * 8;
            ah[rt] = *(const short8*)&Th[gi];
            al[rt] = *(const short8*)&Tl[gi];
        }
#pragma unroll
        for (int rt = 0; rt < 2; rt++)
#pragma unroll
            for (int ct = 0; ct < 4; ct++) {
                acc2[rt][ct] = __builtin_amdgcn_mfma_f32_16x16x32_bf16(ah[rt], wh[ct], acc2[rt][ct], 0, 0, 0);
                acc2[rt][ct] = __builtin_amdgcn_mfma_f32_16x16x32_bf16(ah[rt], wl[ct], acc2[rt][ct], 0, 0, 0);
                acc2[rt][ct] = __builtin_amdgcn_mfma_f32_16x16x32_bf16(al[rt], wh[ct], acc2[rt][ct], 0, 0, 0);
            }
    }
    __syncthreads();

    int colv[4]; float bv[4], gv[4], bbv[4];
#pragma unroll
    for (int ct = 0; ct < 4; ct++) {
        colv[ct] = colbase + 16 * ct + l16;
        bv[ct] = b2[colv[ct]];
        gv[ct] = g2w[colv[ct]];
        bbv[ct] = g2b[colv[ct]];
    }
#pragma unroll
    for (int rt = 0; rt < 2; rt++)
#pragma unroll
    for (int i = 0; i < 4; i++) {
        const int rl = rowbase + 16 * rt + quad * 4 + i;
        float s = 0.f, s2 = 0.f;
#pragma unroll
        for (int ct = 0; ct < 4; ct++) {
            const float c = acc2[rt][ct][i] + bv[ct];
            s += c; s2 += c * c;
        }
#pragma unroll
        for (int o = 8; o > 0; o >>= 1) { s += __shfl_xor(s, o, 64); s2 += __shfl_xor(s2, o, 64); }
        if (l16 == 0) { sredA[rl][colg] = s; sredB[rl][colg] = s2; }
    }
    __syncthreads();
#pragma unroll
    for (int rt = 0; rt < 2; rt++)
#pragma unroll
    for (int i = 0; i < 4; i++) {
        const int rl = rowbase + 16 * rt + quad * 4 + i;
        const float s = sredA[rl][0] + sredA[rl][1] + sredA[rl][2] + sredA[rl][3];
        const float s2 = sredB[rl][0] + sredB[rl][1] + sredB[rl][2] + sredB[rl][3];
        const float mu = s * (1.f / D_);
        const float rs = rsqrtf(s2 * (1.f / D_) - mu * mu + 1e-5f);
#pragma unroll
        for (int ct = 0; ct < 4; ct++) {
            const float c = acc2[rt][ct][i] + bv[ct];
            out[(size_t)(row0 + rl) * D_ + colv[ct]] = split_pack((c - mu) * rs * gv[ct] + bbv[ct]);
        }
    }
}

// ---------- lite MFMA global k-max v2: 256-row blocks (grid 1024) ----------
// Same MFMA shape/operands (h-planes) and zero-C per (rt,ct) product as v1 ->
// dd values bit-identical; max is order-free -> bit-identical slot. P2 staged
// once per 256 rows (4x amortization vs v1), 4x fewer blocks.
__global__ void __launch_bounds__(256) k_dmax(
    const unsigned* __restrict__ kg, const unsigned* __restrict__ P2, int* __restrict__ slot)
{
    __shared__ __align__(16) ushort A2s[256 * 40];
    __shared__ __align__(16) ushort Ps[256 * 40];
    __shared__ float sred[4];
    const int t = threadIdx.x;
    const size_t row0 = (size_t)blockIdx.x * 256;
#pragma unroll
    for (int it = 0; it < 4; it++) {
        const int row = it * 64 + (t >> 2), seg = t & 3;
        const unsigned* src = kg + (row0 + row) * DH_ + seg * 8;
        const uint4 f0 = *(const uint4*)src;
        const uint4 f1 = *(const uint4*)(src + 4);
        *(uint4*)&A2s[row * 40 + seg * 8] =
            make_uint4(hpair(f0.x, f0.y), hpair(f0.z, f0.w), hpair(f1.x, f1.y), hpair(f1.z, f1.w));
    }
    {
        const int col = t;
        const unsigned* src = P2 + (size_t)col * DH_;
#pragma unroll
        for (int hf = 0; hf < 2; hf++) {
            const uint4 g0 = *(const uint4*)(src + hf * 16);
            const uint4 g1 = *(const uint4*)(src + hf * 16 + 4);
            const uint4 g2 = *(const uint4*)(src + hf * 16 + 8);
            const uint4 g3 = *(const uint4*)(src + hf * 16 + 12);
            *(uint4*)&Ps[col * 40 + hf * 16] =
                make_uint4(hpair(g0.x, g0.y), hpair(g0.z, g0.w), hpair(g1.x, g1.y), hpair(g1.z, g1.w));
            *(uint4*)&Ps[col * 40 + hf * 16 + 8] =
                make_uint4(hpair(g2.x, g2.y), hpair(g2.z, g2.w), hpair(g3.x, g3.y), hpair(g3.z, g3.w));
        }
    }
    __syncthreads();
    const int w = t >> 6, lane = t & 63, quad = lane >> 4, l16 = lane & 15;
    short8 bf[4];
#pragma unroll
    for (int ct = 0; ct < 4; ct++)
        bf[ct] = *(const short8*)&Ps[((w * 4 + ct) * 16 + l16) * 40 + quad * 8];
    float mx = -INFINITY;
#pragma unroll 4
    for (int rt = 0; rt < 16; rt++) {
        const short8 af = *(const short8*)&A2s[(rt * 16 + l16) * 40 + quad * 8];
        floatx4 acc[4];
#pragma unroll
        for (int ct = 0; ct < 4; ct++) {
            acc[ct] = (floatx4){0.f, 0.f, 0.f, 0.f};
            acc[ct] = __builtin_amdgcn_mfma_f32_16x16x32_bf16(af, bf[ct], acc[ct], 0, 0, 0);
        }
#pragma unroll
        for (int ct = 0; ct < 4; ct++)
#pragma unroll
            for (int i = 0; i < 4; i++) mx = fmaxf(mx, acc[ct][i]);
    }
#pragma unroll
    for (int o = 32; o > 0; o >>= 1) mx = fmaxf(mx, __shfl_xor(mx, o, 64));
    if (lane == 0) sred[w] = mx;
    __syncthreads();
    if (t == 0) {
        const float m4 = fmaxf(fmaxf(sred[0], sred[1]), fmaxf(sred[2], sred[3]))
                       * 0.42044820762685725f;
        const int i = __float_as_int(m4);
        atomicMax(slot, (i >= 0) ? i : (i ^ 0x7fffffff));
    }
}

// ---------- performer attention v5d ----------
__global__ void __launch_bounds__(1024) k_attn2(
    const unsigned* __restrict__ qg, const unsigned* __restrict__ kg, const unsigned* __restrict__ vg,
    const unsigned* __restrict__ P2, const int* __restrict__ slot,
    unsigned* __restrict__ outp)
{
    extern __shared__ char smem[];
    ushort* sAh   = (ushort*)(smem);            // [128][40] K h-plane
    ushort* sAl   = (ushort*)(smem + 10240);    // [128][40] K l-plane
    ushort* sBh   = (ushort*)(smem + 20480);    // [64][40] P-quarter h
    ushort* sBl   = (ushort*)(smem + 25600);    // [64][40] P-quarter l
    ushort* kpS   = (ushort*)(smem + 30720);    // [64][136] kp bf16 compact; oRed alias
    ushort* sV    = (ushort*)(smem + 48128);    // [32][136] v bf16 compact
    ushort* sCtx  = (ushort*)(smem + 56832);    // [32][264] ctx bf16 compact
    float* sdk    = (float*)(smem + 73728);     // [128] (+kmax fold)
    float* sdq    = (float*)(smem + 74240);     // [128]
    float* smaxP  = (float*)(smem + 74752);     // [2][128]
    float* sdenP  = smaxP;                      // ALIAS (smaxP dead after dmq)
    float* sksum  = (float*)(smem + 75776);     // [256]
    float* sksP   = (float*)(smem + 76800);     // [16][32]

    const int bh = blockIdx.x;
    const int b = bh >> 3, hh = bh & 7;
    const int t = threadIdx.x;
    const int w = t >> 6, lane = t & 63, quad = lane >> 4, l16 = lane & 15;
    const int wg = w & 7, wh = w >> 3;
    const int nq = wg * 16 + l16;
    const unsigned* kb = kg + (size_t)bh * S_ * DH_;
    const unsigned* qb = qg + (size_t)bh * S_ * DH_;
    const unsigned* vb = vg + (size_t)bh * S_ * DH_;
    const float nrm = 0.42044820762685725f;
    const float diagc = 0.5f * nrm * nrm;
    const float ratio = 0.0625f;

    union U8 { uint4 u; short8 s; };
    union U4 { uint2 u; bfx4 s; };

    float kmaxv;
    { const int iv = *slot; kmaxv = __int_as_float((iv >= 0) ? iv : (iv ^ 0x7fffffff)); }

    short8 qfh, qfl;
    {
        const unsigned* qrow = qb + (size_t)nq * DH_ + quad * 8;
        const uint4 q0 = *(const uint4*)qrow;
        const uint4 q1 = *(const uint4*)(qrow + 4);
        U8 th; th.u = make_uint4(hpair(q0.x, q0.y), hpair(q0.z, q0.w), hpair(q1.x, q1.y), hpair(q1.z, q1.w));
        U8 tl; tl.u = make_uint4(lpair(q0.x, q0.y), lpair(q0.z, q0.w), lpair(q1.x, q1.y), lpair(q1.z, q1.w));
        qfh = th.s; qfl = tl.s;
    }

    if (t < 512) {
        const int row = t >> 2, seg = t & 3;
        const unsigned* src = kb + row * DH_ + seg * 8;
        const uint4 f0 = *(const uint4*)&src[0];
        const uint4 f1 = *(const uint4*)&src[4];
        *(uint4*)&sAh[row * 40 + seg * 8] =
            make_uint4(hpair(f0.x, f0.y), hpair(f0.z, f0.w), hpair(f1.x, f1.y), hpair(f1.z, f1.w));
        *(uint4*)&sAl[row * 40 + seg * 8] =
            make_uint4(lpair(f0.x, f0.y), lpair(f0.z, f0.w), lpair(f1.x, f1.y), lpair(f1.z, f1.w));
    } else {
        const int tt2 = t - 512;
        const int n = tt2 & 127, d0 = (tt2 >> 7) * 8;
        const unsigned* src = vb + n * DH_ + d0;
        const uint4 f0 = *(const uint4*)&src[0];
        const uint4 f1 = *(const uint4*)&src[4];
        const unsigned uu[8] = {f0.x, f0.y, f0.z, f0.w, f1.x, f1.y, f1.z, f1.w};
#pragma unroll
        for (int j = 0; j < 8; j++)
            sV[(d0 + j) * 136 + n] = (ushort)(uu[j] & 0xffffu);
    }
    if (t < 128) {
        float s = 0.f, s2 = 0.f;
#pragma unroll
        for (int d4 = 0; d4 < DH_ / 4; d4++) {
            const uint4 kk = *(const uint4*)&kb[t * DH_ + d4 * 4];
            const float k0 = rec(kk.x), k1 = rec(kk.y), k2 = rec(kk.z), k3 = rec(kk.w);
            s += k0 * k0 + k1 * k1 + k2 * k2 + k3 * k3;
            const uint4 qq = *(const uint4*)&qb[t * DH_ + d4 * 4];
            const float q0 = rec(qq.x), q1 = rec(qq.y), q2 = rec(qq.z), q3 = rec(qq.w);
            s2 += q0 * q0 + q1 * q1 + q2 * q2 + q3 * q3;
        }
        sdk[t] = s * diagc + kmaxv;
        sdq[t] = s2 * diagc;
    }
    __syncthreads();

    floatx4 adq[2][4];
#pragma unroll
    for (int j = 0; j < 2; j++)
#pragma unroll
        for (int mtl = 0; mtl < 4; mtl++) adq[j][mtl] = (floatx4){0.f, 0.f, 0.f, 0.f};

#pragma unroll
    for (int qd = 0; qd < 4; qd++) {
        {
            const int col = t >> 4, ch2 = t & 15;
            const unsigned* src = P2 + (size_t)(qd * 64 + col) * DH_ + ch2 * 2;
            const unsigned u0 = src[0], u1 = src[1];
            ((unsigned*)sBh)[col * 20 + ch2] = hpair(u0, u1);
            ((unsigned*)sBl)[col * 20 + ch2] = lpair(u0, u1);
        }
        __syncthreads();
        floatx4 acc[2];
        acc[0] = (floatx4){0.f, 0.f, 0.f, 0.f};
        acc[1] = (floatx4){0.f, 0.f, 0.f, 0.f};
        {
            const short8 afh = *(const short8*)&sAh[nq * 40 + quad * 8];
            const short8 afl = *(const short8*)&sAl[nq * 40 + quad * 8];
#pragma unroll
            for (int ctl = 0; ctl < 2; ctl++) {
                const int mrow = ((2 * wh + ctl) * 16 + l16) * 40 + quad * 8;
                const short8 bfh = *(const short8*)&sBh[mrow];
                const short8 bfl = *(const short8*)&sBl[mrow];
                acc[ctl] = __builtin_amdgcn_mfma_f32_16x16x32_bf16(afh, bfh, acc[ctl], 0, 0, 0);
                acc[ctl] = __builtin_amdgcn_mfma_f32_16x16x32_bf16(afh, bfl, acc[ctl], 0, 0, 0);
                acc[ctl] = __builtin_amdgcn_mfma_f32_16x16x32_bf16(afl, bfh, acc[ctl], 0, 0, 0);
            }
        }
        float kc[2];
#pragma unroll
        for (int ctl = 0; ctl < 2; ctl++) {
            float kcl = 0.f;
            ushort kh[4];
#pragma unroll
            for (int i = 0; i < 4; i++) {
                const int n = wg * 16 + quad * 4 + i;
                const float kp = ratio * (__expf(acc[ctl][i] * nrm - sdk[n]) + 1e-4f);
                kh[i] = bf16_rn(kp);
                kcl += __uint_as_float((unsigned)kh[i] << 16);
            }
            *(uint2*)&kpS[((2 * wh + ctl) * 16 + l16) * 136 + wg * 16 + quad * 4] =
                make_uint2((unsigned)kh[0] | ((unsigned)kh[1] << 16),
                           (unsigned)kh[2] | ((unsigned)kh[3] << 16));
            kc[ctl] = kcl;
        }
#pragma unroll
        for (int ctl = 0; ctl < 2; ctl++) {
            kc[ctl] += __shfl_xor(kc[ctl], 16, 64);
            kc[ctl] += __shfl_xor(kc[ctl], 32, 64);
        }
        if (quad == 0) {
            sksP[w * 32 + l16] = kc[0];
            sksP[w * 32 + 16 + l16] = kc[1];
        }
        __syncthreads();
        const int qown = (qd & 1) ^ 1;
        if (wh == qown) {
            const int aidx2 = qd >> 1;
#pragma unroll
            for (int mtl = 0; mtl < 4; mtl++) {
                const int prow = (mtl * 16 + l16) * 40 + quad * 8;
                const short8 aPh = *(const short8*)&sBh[prow];
                const short8 aPl = *(const short8*)&sBl[prow];
                adq[aidx2][mtl] = __builtin_amdgcn_mfma_f32_16x16x32_bf16(aPh, qfh, adq[aidx2][mtl], 0, 0, 0);
                adq[aidx2][mtl] = __builtin_amdgcn_mfma_f32_16x16x32_bf16(aPh, qfl, adq[aidx2][mtl], 0, 0, 0);
                adq[aidx2][mtl] = __builtin_amdgcn_mfma_f32_16x16x32_bf16(aPl, qfh, adq[aidx2][mtl], 0, 0, 0);
            }
        } else {
            const int mt = wg & 3, dt = wg >> 2;
            floatx4 cacc = (floatx4){0.f, 0.f, 0.f, 0.f};
#pragma unroll
            for (int ks = 0; ks < 4; ks++) {
                const short8 a = *(const short8*)&kpS[(mt * 16 + l16) * 136 + ks * 32 + quad * 8];
                const short8 bvv = *(const short8*)&sV[(dt * 16 + l16) * 136 + ks * 32 + quad * 8];
                cacc = __builtin_amdgcn_mfma_f32_16x16x32_bf16(a, bvv, cacc, 0, 0, 0);
            }
            ushort ch[4];
#pragma unroll
            for (int i = 0; i < 4; i++) ch[i] = bf16_rn(cacc[i]);
            *(uint2*)&sCtx[(dt * 16 + l16) * 264 + qd * 64 + mt * 16 + quad * 4] =
                make_uint2((unsigned)ch[0] | ((unsigned)ch[1] << 16),
                           (unsigned)ch[2] | ((unsigned)ch[3] << 16));
        }
        if (t < 64) {
            float s = 0.f;
#pragma unroll
            for (int wg2 = 0; wg2 < 8; wg2++)
                s += sksP[((t >> 5) * 8 + wg2) * 32 + (t & 31)];
            sksum[qd * 64 + t] = s;
        }
        __syncthreads();
    }

    {
        float mxn = -INFINITY;
#pragma unroll
        for (int j = 0; j < 2; j++)
#pragma unroll
            for (int mtl = 0; mtl < 4; mtl++)
#pragma unroll
                for (int i = 0; i < 4; i++) mxn = fmaxf(mxn, adq[j][mtl][i]);
        mxn = fmaxf(mxn, __shfl_xor(mxn, 16, 64));
        mxn = fmaxf(mxn, __shfl_xor(mxn, 32, 64));
        if (quad == 0) smaxP[wh * 128 + nq] = mxn;
    }
    __syncthreads();
    const float dmq = sdq[nq] + fmaxf(smaxP[nq], smaxP[128 + nq]) * nrm;

    floatx4 oT[2];
    oT[0] = (floatx4){0.f, 0.f, 0.f, 0.f};
    oT[1] = (floatx4){0.f, 0.f, 0.f, 0.f};
    float dp = 0.f;
#pragma unroll
    for (int j = 0; j < 2; j++) {
        const int qdo = 2 * j + (wh ^ 1);
#pragma unroll
        for (int mtl = 0; mtl < 4; mtl++) {
            ushort qh[4];
#pragma unroll
            for (int i = 0; i < 4; i++) {
                const float qp = ratio * (__expf(adq[j][mtl][i] * nrm - dmq) + 1e-4f);
                qh[i] = bf16_rn(qp);
                dp += __uint_as_float((unsigned)qh[i] << 16)
                    * sksum[qdo * 64 + mtl * 16 + quad * 4 + i];
            }
            U4 tb;
            tb.u = make_uint2((unsigned)qh[0] | ((unsigned)qh[1] << 16),
                              (unsigned)qh[2] | ((unsigned)qh[3] << 16));
#pragma unroll
            for (int dt = 0; dt < 2; dt++) {
                U4 ta;
                ta.u = *(const uint2*)&sCtx[(dt * 16 + l16) * 264 + qdo * 64 + mtl * 16 + quad * 4];
                oT[dt] = __builtin_amdgcn_mfma_f32_16x16x16bf16_1k(ta.s, tb.s, oT[dt], 0, 0, 0);
            }
        }
    }
    dp += __shfl_xor(dp, 16, 64);
    dp += __shfl_xor(dp, 32, 64);
    __syncthreads();   // all smaxP reads (dmq) done before sdenP overlay writes
    if (quad == 0) sdenP[wh * 128 + nq] = dp;

    float* oRed = (float*)kpS;
    if (wh == 1) {
#pragma unroll
        for (int dt = 0; dt < 2; dt++)
            *(floatx4*)&oRed[((wg * 2 + dt) * 64 + lane) * 4] = oT[dt];
    }
    __syncthreads();
    if (wh == 0) {
        const float inv = 1.0f / (sdenP[nq] + sdenP[128 + nq]);
#pragma unroll
        for (int dt = 0; dt < 2; dt++) {
            const floatx4 o2 = *(const floatx4*)&oRed[((wg * 2 + dt) * 64 + lane) * 4];
            const unsigned r0 = split_pack((oT[dt][0] + o2[0]) * inv);
            const unsigned r1 = split_pack((oT[dt][1] + o2[1]) * inv);
            const unsigned r2 = split_pack((oT[dt][2] + o2[2]) * inv);
            const unsigned r3 = split_pack((oT[dt][3] + o2[3]) * inv);
            *(uint4*)&outp[((size_t)b * S_ + nq) * D_ + hh * DH_ + dt * 16 + quad * 4] =
                make_uint4(r0, r1, r2, r3);
        }
    }
}

// ---------- classification head (packed input) ----------
__global__ void __launch_bounds__(256) k_head(
    const unsigned* __restrict__ hfin, const float* __restrict__ h1w, const float* __restrict__ h1b,
    const float* __restrict__ h2w, const float* __restrict__ h2b,
    const float* __restrict__ ow, const float* __restrict__ ob, float* __restrict__ outp)
{
    __shared__ float c0[D_];
    __shared__ float c1[2 * HID_];
    __shared__ float sred[4];
    const int t = threadIdx.x;
    const int b = blockIdx.x;
    c0[t] = rec(hfin[(size_t)b * S_ * D_ + t]);
    __syncthreads();
#pragma unroll
    for (int half = 0; half < 2; half++) {
        const int j = half * 256 + t;
        float a = h1b[j];
        const float* w = h1w + (size_t)j * D_;
        for (int d = 0; d < D_; d += 4) {
            const float4 w4 = *(const float4*)&w[d];
            const float4 x4 = *(const float4*)&c0[d];
            a += x4.x * w4.x + x4.y * w4.y + x4.z * w4.z + x4.w * w4.w;
        }
        c1[j] = (a >= 0.f) ? a : 0.2f * a;
    }
    __syncthreads();
    float a2 = h2b[t];
    const float* w2 = h2w + (size_t)t * (2 * HID_);
    for (int j = 0; j < 2 * HID_; j += 4) {
        const float4 w4 = *(const float4*)&w2[j];
        const float4 x4 = *(const float4*)&c1[j];
        a2 += x4.x * w4.x + x4.y * w4.y + x4.z * w4.z + x4.w * w4.w;
    }
    const float c2 = (a2 >= 0.f) ? a2 : 0.2f * a2;
    const float s = blk_sum(c2 * ow[t], sred);
    if (t == 0) outp[b] = s + ob[0];
}

extern "C" void kernel_launch(void* const* d_in, const int* in_sizes, int n_in,
                              void* d_out, int out_size, void* d_ws, size_t ws_size,
                              hipStream_t stream)
{
    const float* x     = (const float*)d_in[0];
    const int*   mask  = (const int*)d_in[1];
    const float* emb_w = (const float*)d_in[2];
    const float* emb_b = (const float*)d_in[3];
    const float* Wq    = (const float*)d_in[4];
    const float* bq    = (const float*)d_in[5];
    const float* Wk    = (const float*)d_in[6];
    const float* bk    = (const float*)d_in[7];
    const float* Wv    = (const float*)d_in[8];
    const float* bv    = (const float*)d_in[9];
    const float* Wo    = (const float*)d_in[10];
    const float* bo    = (const float*)d_in[11];
    const float* proj  = (const float*)d_in[12];
    const float* n1w   = (const float*)d_in[13];
    const float* n1b   = (const float*)d_in[14];
    const float* n2w   = (const float*)d_in[15];
    const float* n2b   = (const float*)d_in[16];
    const float* f1w   = (const float*)d_in[17];
    const float* f1b   = (const float*)d_in[18];
    const float* f2w   = (const float*)d_in[19];
    const float* f2b   = (const float*)d_in[20];
    const float* h1w   = (const float*)d_in[21];
    const float* h1b   = (const float*)d_in[22];
    const float* h2w   = (const float*)d_in[23];
    const float* h2b   = (const float*)d_in[24];
    const float* ow    = (const float*)d_in[25];
    const float* ob    = (const float*)d_in[26];

    const size_t BSD = (size_t)B_ * S_ * D_;
    unsigned* A = (unsigned*)d_ws;                 // packed activations
    unsigned* Q = A + BSD;
    unsigned* K = Q + BSD;
    unsigned* V = K + BSD;
    const size_t WMU = 65536;                      // ushorts per matrix plane (256x256)
    ushort* WH = (ushort*)(V + BSD);               // 6 x L x 65536 ushorts (h planes)
    ushort* WL = WH + 6 * L_ * WMU;                // 6 x L x 65536 ushorts (l planes)
    unsigned* P2 = (unsigned*)(WL + 6 * L_ * WMU); // compact split proj: L x 256 x 32 uints
    int* slots = (int*)(P2 + (size_t)L_ * M_ * DH_);

    // fused prep: weights + proj + reset + embedding (blocks 801..8992)
    k_prep<<<801 + 8192, 256, 0, stream>>>(Wq, Wk, Wv, Wo, f1w, f2w, proj, WH, WL, P2, slots,
                                           x, emb_w, emb_b, A);

    const int GB2 = B_ * S_ / 128;             // 256 blocks per 128-row GEMM
    const int DB = B_ * H_ * S_ / 256;         // 1024 blocks for k_dmax v2
    const size_t ATTN_LDS = 78848;             // 77 KB dynamic LDS

    for (int l = 0; l < L_; l++) {
        const unsigned* P2l = P2 + (size_t)l * M_ * DH_;
        k_gemm_qkv<<<3 * GB2, 512, 0, stream>>>(A, WH, WL, l, bq + l * D_, bk + l * D_, bv + l * D_, mask, Q, K, V);
        k_dmax<<<DB, 256, 0, stream>>>(K, P2l, slots + l);
        k_attn2<<<B_ * H_, 1024, ATTN_LDS, stream>>>(Q, K, V, P2l, slots + l, A);
        k_wofn<<<B_ * S_ / 64, 512, 0, stream>>>(A,
            WH + (3 * L_ + l) * WMU, WL + (3 * L_ + l) * WMU,
            WH + (4 * L_ + l) * WMU, WL + (4 * L_ + l) * WMU,
            WH + (5 * L_ + l) * WMU, WL + (5 * L_ + l) * WMU,
            bo + l * D_, n1w + l * D_, n1b + l * D_,
            f1b + l * HID_, f2b + l * D_, n2w + l * D_, n2b + l * D_, A);
    }
    k_head<<<B_, 256, 0, stream>>>(A, h1w, h1b, h2w, h2b, ow, ob, (float*)d_out);
}